// Round 2
// baseline (5923.964 us; speedup 1.0000x reference)
//
#include <hip/hip_runtime.h>
#include <hip/hip_bf16.h>
#include <math.h>

#define H_ 16
#define E_ 8
#define D_ 1024
#define P_ 64
#define PV_ 64
#define B_ 8
#define T_ 512
#define R_ 1023
#define BT_ 4096
#define CAP_ 4096

typedef __attribute__((ext_vector_type(8))) unsigned short ushort8;

__device__ inline float bf2f(unsigned short u) {
  union { unsigned int i; float f; } c; c.i = ((unsigned int)u) << 16; return c.f;
}

// ---------------------------------------------------------------- zero counts
__global__ void zero_cnt_kernel(int* __restrict__ cnt) {
  int i = threadIdx.x;
  if (i < 512) cnt[i] = 0;
}

// ---------------------------------------------------------------- gates
// block = 128 threads, handles 4 bt rows. he = tid (h*8+e).
__global__ __launch_bounds__(128) void gates_kernel(
    const float* __restrict__ x, const float* __restrict__ wso,
    const float* __restrict__ wsv, int* __restrict__ cnt,
    int* __restrict__ lidx, float* __restrict__ lg,
    int* __restrict__ qo_e, float* __restrict__ qo_g) {
  __shared__ __align__(16) float xs[4][D_];
  __shared__ float gv[4][2][H_][E_];
  int tid = threadIdx.x;
  int bt0 = blockIdx.x * 4;

  const float4* xr = (const float4*)(x + (size_t)bt0 * D_);
  float4* xs4 = (float4*)xs;
  for (int i = tid; i < D_; i += 128) xs4[i] = xr[i];  // 4 rows * 256 float4
  __syncthreads();

  int he = tid;
  const float4* w0 = (const float4*)(wso + (size_t)he * D_);
  const float4* w1 = (const float4*)(wsv + (size_t)he * D_);
  float a0[4] = {0.f, 0.f, 0.f, 0.f}, a1[4] = {0.f, 0.f, 0.f, 0.f};
  for (int i = 0; i < D_ / 4; i++) {
    float4 wv0 = w0[i], wv1 = w1[i];
#pragma unroll
    for (int r = 0; r < 4; r++) {
      float4 xv = ((const float4*)xs[r])[i];
      a0[r] += xv.x * wv0.x + xv.y * wv0.y + xv.z * wv0.z + xv.w * wv0.w;
      a1[r] += xv.x * wv1.x + xv.y * wv1.y + xv.z * wv1.z + xv.w * wv1.w;
    }
  }
  int h = he >> 3, e = he & 7;
#pragma unroll
  for (int r = 0; r < 4; r++) {
    gv[r][0][h][e] = 1.f / (1.f + expf(-a0[r]));
    gv[r][1][h][e] = 1.f / (1.f + expf(-a1[r]));
  }
  __syncthreads();

  // 128 threads = 4 rows x 2 sets x 16 heads : top-2 per (row,set,h)
  {
    int r = tid >> 5, set = (tid >> 4) & 1, hh = tid & 15;
    int bt = bt0 + r;
    const float* g = gv[r][set][hh];
    int i1 = 0; float v1 = g[0];
    for (int ee = 1; ee < 8; ee++) if (g[ee] > v1) { v1 = g[ee]; i1 = ee; }
    int i2 = (i1 == 0) ? 1 : 0; float v2 = g[i2];
    for (int ee = 0; ee < 8; ee++) {
      if (ee == i1) continue;
      if (g[ee] > v2) { v2 = g[ee]; i2 = ee; }
    }
    int base1 = ((set * H_ + hh) * E_ + i1) * 2 + 0;
    int p1 = atomicAdd(&cnt[base1], 1);
    lidx[(size_t)base1 * CAP_ + p1] = bt;
    lg[(size_t)base1 * CAP_ + p1] = v1;
    int base2 = ((set * H_ + hh) * E_ + i2) * 2 + 1;
    int p2 = atomicAdd(&cnt[base2], 1);
    lidx[(size_t)base2 * CAP_ + p2] = bt;
    lg[(size_t)base2 * CAP_ + p2] = v2;
    if (set == 0) {
      qo_e[((size_t)bt * H_ + hh) * 2 + 0] = i1;
      qo_e[((size_t)bt * H_ + hh) * 2 + 1] = i2;
      qo_g[((size_t)bt * H_ + hh) * 2 + 0] = v1;
      qo_g[((size_t)bt * H_ + hh) * 2 + 1] = v2;
    }
  }
}

// ---------------------------------------------------------------- gather GEMM
// grid (128 he, 64 tiles). 64 gathered rows x 64 cols, K=1024.
// slot 0 writes '=', slot 1 writes '+=' (launched after slot 0).
// Output is bf16.
__global__ __launch_bounds__(256) void proj_kernel(
    const float* __restrict__ x, const float* __restrict__ W,
    const int* __restrict__ cnt, const int* __restrict__ lidx,
    const float* __restrict__ lg, __hip_bfloat16* __restrict__ out,
    int set, int slot) {
  int he = blockIdx.x;
  int tile = blockIdx.y;
  int base = (set * 128 + he) * 2 + slot;
  int n = cnt[base];
  int start = tile * 64;
  if (start >= n) return;
  int m = min(64, n - start);

  __shared__ int ridx[64];
  __shared__ float rgs[64];
  __shared__ float xs[64][33];
  __shared__ float wsm[32][65];
  int tid = threadIdx.x;
  if (tid < 64) {
    int v = 0; float g = 0.f;
    if (tid < m) {
      v = lidx[(size_t)base * CAP_ + start + tid];
      g = lg[(size_t)base * CAP_ + start + tid];
    }
    ridx[tid] = v; rgs[tid] = g;
  }
  __syncthreads();

  float acc[4][4] = {};
  int r0 = (tid >> 4) * 4, c0 = (tid & 15) * 4;
  const float* Wb = W + (size_t)he * D_ * P_;
  for (int d0 = 0; d0 < D_; d0 += 32) {
    for (int i = tid; i < 64 * 32; i += 256) {
      int r = i >> 5, d = i & 31;
      xs[r][d] = x[(size_t)ridx[r] * D_ + d0 + d];
    }
    for (int i = tid; i < 32 * 64; i += 256) {
      int dr = i >> 6, p = i & 63;
      wsm[dr][p] = Wb[(size_t)(d0 + dr) * P_ + p];
    }
    __syncthreads();
#pragma unroll
    for (int d = 0; d < 32; d++) {
      float xv[4], wv[4];
#pragma unroll
      for (int i2 = 0; i2 < 4; i2++) xv[i2] = xs[r0 + i2][d];
#pragma unroll
      for (int j = 0; j < 4; j++) wv[j] = wsm[d][c0 + j];
#pragma unroll
      for (int i2 = 0; i2 < 4; i2++)
#pragma unroll
        for (int j = 0; j < 4; j++) acc[i2][j] += xv[i2] * wv[j];
    }
    __syncthreads();
  }

  int h = he >> 3;
  for (int i2 = 0; i2 < 4; i2++) {
    int r = r0 + i2;
    if (r >= m) break;
    int bt = ridx[r]; float g = rgs[r];
    int b = bt >> 9, t = bt & 511;
    __hip_bfloat16* orow = out + ((size_t)((b * H_ + h) * T_) + t) * P_ + c0;
    if (slot == 0) {
#pragma unroll
      for (int j = 0; j < 4; j++) orow[j] = __float2bfloat16(g * acc[i2][j]);
    } else {
#pragma unroll
      for (int j = 0; j < 4; j++)
        orow[j] = __float2bfloat16(__bfloat162float(orow[j]) + g * acc[i2][j]);
    }
  }
}

// ---------------------------------------------------------------- k_pos GEMM
// kpos[r][h*64+p] = sum_d pe[r][d] * Wpos[h*64+p][d]   (fp32 out)
__global__ __launch_bounds__(256) void kpos_kernel(
    const float* __restrict__ pe, const float* __restrict__ Wp,
    float* __restrict__ kpos) {
  int rt = blockIdx.x;  // 16 tiles of 64 rows (last has 63)
  int ct = blockIdx.y;  // 16 tiles of 64 cols
  __shared__ float ps[64][33];
  __shared__ float wsh[64][33];
  int tid = threadIdx.x;
  float acc[4][4] = {};
  int r0 = (tid >> 4) * 4, c0 = (tid & 15) * 4;
  for (int d0 = 0; d0 < D_; d0 += 32) {
    for (int i = tid; i < 64 * 32; i += 256) {
      int r = i >> 5, d = i & 31;
      int rr = rt * 64 + r;
      ps[r][d] = (rr < R_) ? pe[(size_t)rr * D_ + d0 + d] : 0.f;
    }
    for (int i = tid; i < 64 * 32; i += 256) {
      int c = i >> 5, d = i & 31;
      wsh[c][d] = Wp[(size_t)(ct * 64 + c) * D_ + d0 + d];
    }
    __syncthreads();
#pragma unroll
    for (int d = 0; d < 32; d++) {
      float pv2[4], wv[4];
#pragma unroll
      for (int i2 = 0; i2 < 4; i2++) pv2[i2] = ps[r0 + i2][d];
#pragma unroll
      for (int j = 0; j < 4; j++) wv[j] = wsh[c0 + j][d];
#pragma unroll
      for (int i2 = 0; i2 < 4; i2++)
#pragma unroll
        for (int j = 0; j < 4; j++) acc[i2][j] += pv2[i2] * wv[j];
    }
    __syncthreads();
  }
  for (int i2 = 0; i2 < 4; i2++) {
    int rr = rt * 64 + r0 + i2;
    if (rr >= R_) break;
    for (int j = 0; j < 4; j++)
      kpos[(size_t)rr * 1024 + ct * 64 + c0 + j] = acc[i2][j];
  }
}

// ---------------------------------------------------------------- attention
// one wave per (b,h,t). scores = q . (k[s] + kpos[s-t+511]) for s<=t.
// q,k,v are bf16; kpos fp32; ctx out bf16.
__global__ __launch_bounds__(64) void attn_kernel(
    const __hip_bfloat16* __restrict__ q, const __hip_bfloat16* __restrict__ k,
    const __hip_bfloat16* __restrict__ v, const float* __restrict__ kpos,
    __hip_bfloat16* __restrict__ ctx) {
  int t = blockIdx.x, h = blockIdx.y, b = blockIdx.z;
  int lane = threadIdx.x;
  __shared__ float qs[P_];
  __shared__ float sc[T_];
  qs[lane] = __bfloat162float(q[((size_t)((b * H_ + h) * T_) + t) * P_ + lane]);
  __syncthreads();

  for (int s = lane; s <= t; s += 64) {
    const ushort8* k8 =
        (const ushort8*)((const unsigned short*)k + ((size_t)((b * H_ + h) * T_) + s) * P_);
    int r = s - t + (T_ - 1);
    const float* kpr = kpos + ((size_t)r * H_ + h) * P_;
    float acc = 0.f;
#pragma unroll
    for (int i = 0; i < 8; i++) {
      ushort8 kv = k8[i];
#pragma unroll
      for (int j = 0; j < 8; j++)
        acc += qs[i * 8 + j] * (bf2f(kv[j]) + kpr[i * 8 + j]);
    }
    sc[s] = acc * 0.125f;
  }
  __syncthreads();

  float mx = -1e30f;
  for (int s = lane; s <= t; s += 64) mx = fmaxf(mx, sc[s]);
  for (int off = 32; off; off >>= 1) mx = fmaxf(mx, __shfl_xor(mx, off));
  float sum = 0.f;
  for (int s = lane; s <= t; s += 64) {
    float e2 = expf(sc[s] - mx);
    sc[s] = e2;
    sum += e2;
  }
  for (int off = 32; off; off >>= 1) sum += __shfl_xor(sum, off);
  __syncthreads();
  float inv = 1.f / sum;

  const unsigned short* vb = (const unsigned short*)v + ((size_t)((b * H_ + h) * T_)) * PV_ + lane;
  float acc = 0.f;
  for (int s = 0; s <= t; s++) {
    acc += sc[s] * bf2f(vb[(size_t)s * PV_]);
  }
  ctx[((size_t)(b * T_ + t) * H_ + h) * PV_ + lane] = __float2bfloat16(acc * inv);
}

// ---------------------------------------------------------------- output proj
// grid (64 bt-tiles, 16 d-tiles). loops h, e; LDS-stages ctx & Wo tiles.
__global__ __launch_bounds__(256) void out_kernel(
    const __hip_bfloat16* __restrict__ ctx, const float* __restrict__ Wo,
    const int* __restrict__ qo_e, const float* __restrict__ qo_g,
    float* __restrict__ out) {
  int rt = blockIdx.x;
  int ct = blockIdx.y;
  int tid = threadIdx.x;
  __shared__ float cs[64][65];
  __shared__ float wsh[64][65];
  __shared__ int ge[64][2];
  __shared__ float gg[64][2];
  float acc[4][4] = {};
  int r0 = (tid >> 4) * 4, c0 = (tid & 15) * 4;
  const unsigned short* ctxu = (const unsigned short*)ctx;

  for (int h = 0; h < H_; h++) {
    for (int i = tid; i < 64 * 64; i += 256) {
      int r = i >> 6, pv = i & 63;
      cs[r][pv] = bf2f(ctxu[((size_t)(rt * 64 + r) * H_ + h) * PV_ + pv]);
    }
    if (tid < 128) {
      int r = tid >> 1, s2 = tid & 1;
      ge[r][s2] = qo_e[((size_t)(rt * 64 + r) * H_ + h) * 2 + s2];
      gg[r][s2] = qo_g[((size_t)(rt * 64 + r) * H_ + h) * 2 + s2];
    }
    __syncthreads();
    for (int e = 0; e < E_; e++) {
      for (int i = tid; i < 64 * 64; i += 256) {
        int pv = i >> 6, c = i & 63;
        wsh[pv][c] = Wo[((size_t)(h * E_ + e) * PV_ + pv) * D_ + ct * 64 + c];
      }
      __syncthreads();
#pragma unroll
      for (int i2 = 0; i2 < 4; i2++) {
        int r = r0 + i2;
        float coef = (ge[r][0] == e) ? gg[r][0] : ((ge[r][1] == e) ? gg[r][1] : 0.f);
        if (coef != 0.f) {
          float t0 = 0.f, t1 = 0.f, t2 = 0.f, t3 = 0.f;
          for (int pv = 0; pv < 64; pv++) {
            float cv = cs[r][pv];
            t0 += cv * wsh[pv][c0 + 0];
            t1 += cv * wsh[pv][c0 + 1];
            t2 += cv * wsh[pv][c0 + 2];
            t3 += cv * wsh[pv][c0 + 3];
          }
          acc[i2][0] += coef * t0; acc[i2][1] += coef * t1;
          acc[i2][2] += coef * t2; acc[i2][3] += coef * t3;
        }
      }
      __syncthreads();
    }
  }
  for (int i2 = 0; i2 < 4; i2++)
    for (int j = 0; j < 4; j++)
      out[(size_t)(rt * 64 + r0 + i2) * D_ + ct * 64 + c0 + j] = acc[i2][j];
}

// ---------------------------------------------------------------- launch
extern "C" void kernel_launch(void* const* d_in, const int* in_sizes, int n_in,
                              void* d_out, int out_size, void* d_ws, size_t ws_size,
                              hipStream_t stream) {
  const float* x   = (const float*)d_in[0];
  const float* pe  = (const float*)d_in[1];
  const float* wso = (const float*)d_in[2];
  const float* wsv = (const float*)d_in[3];
  const float* Wq  = (const float*)d_in[4];
  const float* Wk  = (const float*)d_in[5];
  const float* Wv  = (const float*)d_in[6];
  const float* Wo  = (const float*)d_in[7];
  const float* Wp  = (const float*)d_in[8];
  float* out = (float*)d_out;
  char* ws = (char*)d_ws;

  // workspace carve-up (bytes), total = 55,578,624 (~53 MiB)
  int*   cnt  = (int*)  (ws + 0);          // 512 ints          (4 KiB resv)
  int*   qo_e = (int*)  (ws + 4096);       // 4096*16*2 ints    = 512 KiB
  float* qo_g = (float*)(ws + 528384);     // 512 KiB
  int*   lidx = (int*)  (ws + 1052672);    // 512 lists * 4096  = 8 MiB
  float* lg   = (float*)(ws + 9441280);    // 8 MiB
  float* kpos = (float*)(ws + 17829888);   // 1023*1024 f32     = 4 MiB resv
  __hip_bfloat16* q   = (__hip_bfloat16*)(ws + 22024192);  // 8 MiB (B,H,T,P) bf16
  __hip_bfloat16* k   = (__hip_bfloat16*)(ws + 30412800);  // 8 MiB
  __hip_bfloat16* v   = (__hip_bfloat16*)(ws + 38801408);  // 8 MiB
  __hip_bfloat16* ctx = (__hip_bfloat16*)(ws + 47190016);  // 8 MiB (B,T,H,PV) bf16

  hipLaunchKernelGGL(zero_cnt_kernel, dim3(1), dim3(512), 0, stream, cnt);
  hipLaunchKernelGGL(gates_kernel, dim3(BT_ / 4), dim3(128), 0, stream,
                     x, wso, wsv, cnt, lidx, lg, qo_e, qo_g);
  hipLaunchKernelGGL(kpos_kernel, dim3(16, 16), dim3(256), 0, stream, pe, Wp, kpos);

  // q (set 0), k,v (set 1); slot 0 then slot 1 (stream-ordered)
  hipLaunchKernelGGL(proj_kernel, dim3(128, 64), dim3(256), 0, stream,
                     x, Wq, cnt, lidx, lg, q, 0, 0);
  hipLaunchKernelGGL(proj_kernel, dim3(128, 64), dim3(256), 0, stream,
                     x, Wq, cnt, lidx, lg, q, 0, 1);
  hipLaunchKernelGGL(proj_kernel, dim3(128, 64), dim3(256), 0, stream,
                     x, Wk, cnt, lidx, lg, k, 1, 0);
  hipLaunchKernelGGL(proj_kernel, dim3(128, 64), dim3(256), 0, stream,
                     x, Wk, cnt, lidx, lg, k, 1, 1);
  hipLaunchKernelGGL(proj_kernel, dim3(128, 64), dim3(256), 0, stream,
                     x, Wv, cnt, lidx, lg, v, 1, 0);
  hipLaunchKernelGGL(proj_kernel, dim3(128, 64), dim3(256), 0, stream,
                     x, Wv, cnt, lidx, lg, v, 1, 1);

  hipLaunchKernelGGL(attn_kernel, dim3(T_, H_, B_), dim3(64), 0, stream,
                     q, k, v, kpos, ctx);
  hipLaunchKernelGGL(out_kernel, dim3(64, 16), dim3(256), 0, stream,
                     ctx, Wo, qo_e, qo_g, out);
}

// Round 3
// 3775.330 us; speedup vs baseline: 1.5691x; 1.5691x over previous
//
#include <hip/hip_runtime.h>
#include <hip/hip_bf16.h>
#include <math.h>

#define H_ 16
#define E_ 8
#define D_ 1024
#define P_ 64
#define PV_ 64
#define B_ 8
#define T_ 512
#define R_ 1023
#define BT_ 4096
#define CAP_ 4096

typedef __attribute__((ext_vector_type(8))) unsigned short ushort8;
typedef __attribute__((ext_vector_type(8))) short short8;
typedef __attribute__((ext_vector_type(4))) float f32x4;

__device__ inline float bf2f(unsigned short u) {
  union { unsigned int i; float f; } c; c.i = ((unsigned int)u) << 16; return c.f;
}
__device__ inline unsigned short f2bf(float f) {
  __hip_bfloat16 h = __float2bfloat16(f);
  return *reinterpret_cast<unsigned short*>(&h);
}

// ---------------------------------------------------------------- zero counts
__global__ void zero_cnt_kernel(int* __restrict__ cnt) {
  int i = threadIdx.x;
  if (i < 512) cnt[i] = 0;
}

// ---------------------------------------------------------------- gates
// block = 128 threads, handles 4 bt rows. he = tid (h*8+e).
// Emits gather lists (both sets) and a dense coefs[bt][h][e] table for set 0.
__global__ __launch_bounds__(128) void gates_kernel(
    const float* __restrict__ x, const float* __restrict__ wso,
    const float* __restrict__ wsv, int* __restrict__ cnt,
    int* __restrict__ lidx, float* __restrict__ lg,
    float* __restrict__ coefs) {
  __shared__ __align__(16) float xs[4][D_];
  __shared__ float gv[4][2][H_][E_];
  int tid = threadIdx.x;
  int bt0 = blockIdx.x * 4;

  const float4* xr = (const float4*)(x + (size_t)bt0 * D_);
  float4* xs4 = (float4*)xs;
  for (int i = tid; i < D_; i += 128) xs4[i] = xr[i];
  __syncthreads();

  int he = tid;
  const float4* w0 = (const float4*)(wso + (size_t)he * D_);
  const float4* w1 = (const float4*)(wsv + (size_t)he * D_);
  float a0[4] = {0.f, 0.f, 0.f, 0.f}, a1[4] = {0.f, 0.f, 0.f, 0.f};
  for (int i = 0; i < D_ / 4; i++) {
    float4 wv0 = w0[i], wv1 = w1[i];
#pragma unroll
    for (int r = 0; r < 4; r++) {
      float4 xv = ((const float4*)xs[r])[i];
      a0[r] += xv.x * wv0.x + xv.y * wv0.y + xv.z * wv0.z + xv.w * wv0.w;
      a1[r] += xv.x * wv1.x + xv.y * wv1.y + xv.z * wv1.z + xv.w * wv1.w;
    }
  }
  int h = he >> 3, e = he & 7;
#pragma unroll
  for (int r = 0; r < 4; r++) {
    gv[r][0][h][e] = 1.f / (1.f + expf(-a0[r]));
    gv[r][1][h][e] = 1.f / (1.f + expf(-a1[r]));
  }
  __syncthreads();

  // 128 threads = 4 rows x 2 sets x 16 heads : top-2 per (row,set,h)
  {
    int r = tid >> 5, set = (tid >> 4) & 1, hh = tid & 15;
    int bt = bt0 + r;
    const float* g = gv[r][set][hh];
    int i1 = 0; float v1 = g[0];
    for (int ee = 1; ee < 8; ee++) if (g[ee] > v1) { v1 = g[ee]; i1 = ee; }
    int i2 = (i1 == 0) ? 1 : 0; float v2 = g[i2];
    for (int ee = 0; ee < 8; ee++) {
      if (ee == i1) continue;
      if (g[ee] > v2) { v2 = g[ee]; i2 = ee; }
    }
    int base1 = ((set * H_ + hh) * E_ + i1) * 2 + 0;
    int p1 = atomicAdd(&cnt[base1], 1);
    lidx[(size_t)base1 * CAP_ + p1] = bt;
    lg[(size_t)base1 * CAP_ + p1] = v1;
    int base2 = ((set * H_ + hh) * E_ + i2) * 2 + 1;
    int p2 = atomicAdd(&cnt[base2], 1);
    lidx[(size_t)base2 * CAP_ + p2] = bt;
    lg[(size_t)base2 * CAP_ + p2] = v2;
    if (set == 0) {
#pragma unroll
      for (int ee = 0; ee < 8; ee++) {
        float c = (ee == i1) ? v1 : ((ee == i2) ? v2 : 0.f);
        coefs[((size_t)bt * H_ + hh) * E_ + ee] = c;
      }
    }
  }
}

// ---------------------------------------------------------------- gather GEMM
// grid (128 he, 64 tiles). 64 gathered rows x 64 cols, K=1024. bf16 out.
__global__ __launch_bounds__(256) void proj_kernel(
    const float* __restrict__ x, const float* __restrict__ W,
    const int* __restrict__ cnt, const int* __restrict__ lidx,
    const float* __restrict__ lg, __hip_bfloat16* __restrict__ out,
    int set, int slot) {
  int he = blockIdx.x;
  int tile = blockIdx.y;
  int base = (set * 128 + he) * 2 + slot;
  int n = cnt[base];
  int start = tile * 64;
  if (start >= n) return;
  int m = min(64, n - start);

  __shared__ int ridx[64];
  __shared__ float rgs[64];
  __shared__ float xs[64][33];
  __shared__ float wsm[32][65];
  int tid = threadIdx.x;
  if (tid < 64) {
    int v = 0; float g = 0.f;
    if (tid < m) {
      v = lidx[(size_t)base * CAP_ + start + tid];
      g = lg[(size_t)base * CAP_ + start + tid];
    }
    ridx[tid] = v; rgs[tid] = g;
  }
  __syncthreads();

  float acc[4][4] = {};
  int r0 = (tid >> 4) * 4, c0 = (tid & 15) * 4;
  const float* Wb = W + (size_t)he * D_ * P_;
  for (int d0 = 0; d0 < D_; d0 += 32) {
    for (int i = tid; i < 64 * 32; i += 256) {
      int r = i >> 5, d = i & 31;
      xs[r][d] = x[(size_t)ridx[r] * D_ + d0 + d];
    }
    for (int i = tid; i < 32 * 64; i += 256) {
      int dr = i >> 6, p = i & 63;
      wsm[dr][p] = Wb[(size_t)(d0 + dr) * P_ + p];
    }
    __syncthreads();
#pragma unroll
    for (int d = 0; d < 32; d++) {
      float xv[4], wv[4];
#pragma unroll
      for (int i2 = 0; i2 < 4; i2++) xv[i2] = xs[r0 + i2][d];
#pragma unroll
      for (int j = 0; j < 4; j++) wv[j] = wsm[d][c0 + j];
#pragma unroll
      for (int i2 = 0; i2 < 4; i2++)
#pragma unroll
        for (int j = 0; j < 4; j++) acc[i2][j] += xv[i2] * wv[j];
    }
    __syncthreads();
  }

  int h = he >> 3;
  for (int i2 = 0; i2 < 4; i2++) {
    int r = r0 + i2;
    if (r >= m) break;
    int bt = ridx[r]; float g = rgs[r];
    int b = bt >> 9, t = bt & 511;
    __hip_bfloat16* orow = out + ((size_t)((b * H_ + h) * T_) + t) * P_ + c0;
    if (slot == 0) {
#pragma unroll
      for (int j = 0; j < 4; j++) orow[j] = __float2bfloat16(g * acc[i2][j]);
    } else {
#pragma unroll
      for (int j = 0; j < 4; j++)
        orow[j] = __float2bfloat16(__bfloat162float(orow[j]) + g * acc[i2][j]);
    }
  }
}

// ---------------------------------------------------------------- k_pos GEMM
__global__ __launch_bounds__(256) void kpos_kernel(
    const float* __restrict__ pe, const float* __restrict__ Wp,
    float* __restrict__ kpos) {
  int rt = blockIdx.x;
  int ct = blockIdx.y;
  __shared__ float ps[64][33];
  __shared__ float wsh[64][33];
  int tid = threadIdx.x;
  float acc[4][4] = {};
  int r0 = (tid >> 4) * 4, c0 = (tid & 15) * 4;
  for (int d0 = 0; d0 < D_; d0 += 32) {
    for (int i = tid; i < 64 * 32; i += 256) {
      int r = i >> 5, d = i & 31;
      int rr = rt * 64 + r;
      ps[r][d] = (rr < R_) ? pe[(size_t)rr * D_ + d0 + d] : 0.f;
    }
    for (int i = tid; i < 64 * 32; i += 256) {
      int c = i >> 5, d = i & 31;
      wsh[c][d] = Wp[(size_t)(ct * 64 + c) * D_ + d0 + d];
    }
    __syncthreads();
#pragma unroll
    for (int d = 0; d < 32; d++) {
      float pv2[4], wv[4];
#pragma unroll
      for (int i2 = 0; i2 < 4; i2++) pv2[i2] = ps[r0 + i2][d];
#pragma unroll
      for (int j = 0; j < 4; j++) wv[j] = wsh[c0 + j][d];
#pragma unroll
      for (int i2 = 0; i2 < 4; i2++)
#pragma unroll
        for (int j = 0; j < 4; j++) acc[i2][j] += pv2[i2] * wv[j];
    }
    __syncthreads();
  }
  for (int i2 = 0; i2 < 4; i2++) {
    int rr = rt * 64 + r0 + i2;
    if (rr >= R_) break;
    for (int j = 0; j < 4; j++)
      kpos[(size_t)rr * 1024 + ct * 64 + c0 + j] = acc[i2][j];
  }
}

// ---------------------------------------------------------------- attention
__global__ __launch_bounds__(64) void attn_kernel(
    const __hip_bfloat16* __restrict__ q, const __hip_bfloat16* __restrict__ k,
    const __hip_bfloat16* __restrict__ v, const float* __restrict__ kpos,
    __hip_bfloat16* __restrict__ ctx) {
  int t = blockIdx.x, h = blockIdx.y, b = blockIdx.z;
  int lane = threadIdx.x;
  __shared__ float qs[P_];
  __shared__ float sc[T_];
  qs[lane] = __bfloat162float(q[((size_t)((b * H_ + h) * T_) + t) * P_ + lane]);
  __syncthreads();

  for (int s = lane; s <= t; s += 64) {
    const ushort8* k8 =
        (const ushort8*)((const unsigned short*)k + ((size_t)((b * H_ + h) * T_) + s) * P_);
    int r = s - t + (T_ - 1);
    const float* kpr = kpos + ((size_t)r * H_ + h) * P_;
    float acc = 0.f;
#pragma unroll
    for (int i = 0; i < 8; i++) {
      ushort8 kv = k8[i];
#pragma unroll
      for (int j = 0; j < 8; j++)
        acc += qs[i * 8 + j] * (bf2f(kv[j]) + kpr[i * 8 + j]);
    }
    sc[s] = acc * 0.125f;
  }
  __syncthreads();

  float mx = -1e30f;
  for (int s = lane; s <= t; s += 64) mx = fmaxf(mx, sc[s]);
  for (int off = 32; off; off >>= 1) mx = fmaxf(mx, __shfl_xor(mx, off));
  float sum = 0.f;
  for (int s = lane; s <= t; s += 64) {
    float e2 = expf(sc[s] - mx);
    sc[s] = e2;
    sum += e2;
  }
  for (int off = 32; off; off >>= 1) sum += __shfl_xor(sum, off);
  __syncthreads();
  float inv = 1.f / sum;

  const unsigned short* vb = (const unsigned short*)v + ((size_t)((b * H_ + h) * T_)) * PV_ + lane;
  float acc = 0.f;
  for (int s = 0; s <= t; s++) {
    acc += sc[s] * bf2f(vb[(size_t)s * PV_]);
  }
  ctx[((size_t)(b * T_ + t) * H_ + h) * PV_ + lane] = __float2bfloat16(acc * inv);
}

// ---------------------------------------------------------------- Wo transpose
// Wo fp32 is [k=8192][d=1024] row-major; emit Wob bf16 [d=1024][k=8192].
__global__ __launch_bounds__(256) void wo_transpose_kernel(
    const float* __restrict__ Wo, __hip_bfloat16* __restrict__ Wob) {
  __shared__ float t[64][65];
  int kt = blockIdx.x, dt = blockIdx.y;  // 128 x 16
  int tid = threadIdx.x;
  int kr = tid >> 2, dseg = (tid & 3) * 16;
  const float4* src = (const float4*)&Wo[(size_t)(kt * 64 + kr) * 1024 + dt * 64 + dseg];
#pragma unroll
  for (int i = 0; i < 4; ++i) {
    float4 v4 = src[i];
    t[kr][dseg + i * 4 + 0] = v4.x;
    t[kr][dseg + i * 4 + 1] = v4.y;
    t[kr][dseg + i * 4 + 2] = v4.z;
    t[kr][dseg + i * 4 + 3] = v4.w;
  }
  __syncthreads();
  int dr = tid >> 2, kseg = (tid & 3) * 16;
  unsigned short* dst =
      (unsigned short*)Wob + (size_t)(dt * 64 + dr) * 8192 + kt * 64 + kseg;
#pragma unroll
  for (int half = 0; half < 2; ++half) {
    ushort8 o;
#pragma unroll
    for (int j = 0; j < 8; ++j) o[j] = f2bf(t[kseg + half * 8 + j][dr]);
    *(ushort8*)&dst[half * 8] = o;
  }
}

// ---------------------------------------------------------------- MoE out GEMM
// out[4096][1024] = A[4096][8192] x B[8192][1024]
// A[bt][he*64+pv] = coefs[bt][he] * ctx[bt][h][pv]  (built on the fly)
// B[k][d] = Wo; staged from Wob[d][k] (transposed, bf16).
__global__ __launch_bounds__(256) void moe_out_gemm(
    const __hip_bfloat16* __restrict__ ctx, const float* __restrict__ coefs,
    const __hip_bfloat16* __restrict__ Wob, float* __restrict__ out) {
  __shared__ __align__(16) unsigned short As[128][72];
  __shared__ __align__(16) unsigned short Bs[128][72];
  int tid = threadIdx.x;
  int mt = blockIdx.x, nt = blockIdx.y;
  int wave = tid >> 6, lane = tid & 63;
  int wr = wave >> 1, wc = wave & 1;
  int lrow = lane & 15, lk = (lane >> 4) << 3;

  f32x4 acc[4][4] = {};

  int arow = tid >> 1;         // 0..127
  int aseg = (tid & 1) * 32;   // element seg within 64
  const unsigned short* ctxu = (const unsigned short*)ctx;
  const unsigned short* wobu = (const unsigned short*)Wob;
  size_t grow = (size_t)mt * 128 + arow;

  for (int he = 0; he < 128; ++he) {
    int h = he >> 3;
    float cf = coefs[grow * 128 + he];
    const ushort8* asrc = (const ushort8*)&ctxu[(grow * 16 + h) * 64 + aseg];
    const ushort8* bsrc =
        (const ushort8*)&wobu[((size_t)nt * 128 + arow) * 8192 + he * 64 + aseg];
#pragma unroll
    for (int i = 0; i < 4; ++i) {
      ushort8 u = asrc[i];
      ushort8 o;
#pragma unroll
      for (int j = 0; j < 8; ++j) o[j] = f2bf(bf2f(u[j]) * cf);
      *(ushort8*)&As[arow][aseg + i * 8] = o;
      *(ushort8*)&Bs[arow][aseg + i * 8] = bsrc[i];
    }
    __syncthreads();
#pragma unroll
    for (int kk = 0; kk < 2; ++kk) {
      short8 af[4], bfr[4];
#pragma unroll
      for (int m = 0; m < 4; ++m)
        af[m] = *(const short8*)&As[wr * 64 + m * 16 + lrow][kk * 32 + lk];
#pragma unroll
      for (int n = 0; n < 4; ++n)
        bfr[n] = *(const short8*)&Bs[wc * 64 + n * 16 + lrow][kk * 32 + lk];
#pragma unroll
      for (int m = 0; m < 4; ++m)
#pragma unroll
        for (int n = 0; n < 4; ++n)
          acc[m][n] = __builtin_amdgcn_mfma_f32_16x16x32_bf16(
              af[m], bfr[n], acc[m][n], 0, 0, 0);
    }
    __syncthreads();
  }

  int orow0 = mt * 128 + wr * 64 + (lane >> 4) * 4;
  int ocol0 = nt * 128 + wc * 64 + lrow;
#pragma unroll
  for (int m = 0; m < 4; ++m)
#pragma unroll
    for (int n = 0; n < 4; ++n)
#pragma unroll
      for (int r = 0; r < 4; ++r)
        out[(size_t)(orow0 + m * 16 + r) * 1024 + ocol0 + n * 16] = acc[m][n][r];
}

// ---------------------------------------------------------------- launch
extern "C" void kernel_launch(void* const* d_in, const int* in_sizes, int n_in,
                              void* d_out, int out_size, void* d_ws, size_t ws_size,
                              hipStream_t stream) {
  const float* x   = (const float*)d_in[0];
  const float* pe  = (const float*)d_in[1];
  const float* wso = (const float*)d_in[2];
  const float* wsv = (const float*)d_in[3];
  const float* Wq  = (const float*)d_in[4];
  const float* Wk  = (const float*)d_in[5];
  const float* Wv  = (const float*)d_in[6];
  const float* Wo  = (const float*)d_in[7];
  const float* Wp  = (const float*)d_in[8];
  float* out = (float*)d_out;
  char* ws = (char*)d_ws;

  // workspace carve-up (bytes), total = 56,627,200 (~54 MiB)
  int*   cnt   = (int*)  (ws + 0);           // 512 ints (4 KiB resv)
  float* coefs = (float*)(ws + 4096);        // 4096*16*8 fp32 = 2 MiB
  int*   lidx  = (int*)  (ws + 2101248);     // 8 MiB (gates->proj)
  float* lg    = (float*)(ws + 10489856);    // 8 MiB (gates->proj)
  __hip_bfloat16* Wob = (__hip_bfloat16*)(ws + 2101248);  // 16 MiB, reuses lidx+lg
  float* kpos = (float*)(ws + 18878464);     // 4 MiB resv
  __hip_bfloat16* q   = (__hip_bfloat16*)(ws + 23072768); // 8 MiB (B,H,T,P)
  __hip_bfloat16* k   = (__hip_bfloat16*)(ws + 31461376); // 8 MiB
  __hip_bfloat16* v   = (__hip_bfloat16*)(ws + 39849984); // 8 MiB
  __hip_bfloat16* ctx = (__hip_bfloat16*)(ws + 48238592); // 8 MiB (bt,H,PV)

  hipLaunchKernelGGL(zero_cnt_kernel, dim3(1), dim3(512), 0, stream, cnt);
  hipLaunchKernelGGL(gates_kernel, dim3(BT_ / 4), dim3(128), 0, stream,
                     x, wso, wsv, cnt, lidx, lg, coefs);
  hipLaunchKernelGGL(kpos_kernel, dim3(16, 16), dim3(256), 0, stream, pe, Wp, kpos);

  hipLaunchKernelGGL(proj_kernel, dim3(128, 64), dim3(256), 0, stream,
                     x, Wq, cnt, lidx, lg, q, 0, 0);
  hipLaunchKernelGGL(proj_kernel, dim3(128, 64), dim3(256), 0, stream,
                     x, Wq, cnt, lidx, lg, q, 0, 1);
  hipLaunchKernelGGL(proj_kernel, dim3(128, 64), dim3(256), 0, stream,
                     x, Wk, cnt, lidx, lg, k, 1, 0);
  hipLaunchKernelGGL(proj_kernel, dim3(128, 64), dim3(256), 0, stream,
                     x, Wk, cnt, lidx, lg, k, 1, 1);
  hipLaunchKernelGGL(proj_kernel, dim3(128, 64), dim3(256), 0, stream,
                     x, Wv, cnt, lidx, lg, v, 1, 0);
  hipLaunchKernelGGL(proj_kernel, dim3(128, 64), dim3(256), 0, stream,
                     x, Wv, cnt, lidx, lg, v, 1, 1);

  // lidx/lg are dead after the projections: overwrite with Wob.
  hipLaunchKernelGGL(wo_transpose_kernel, dim3(128, 16), dim3(256), 0, stream,
                     Wo, Wob);

  hipLaunchKernelGGL(attn_kernel, dim3(T_, H_, B_), dim3(64), 0, stream,
                     q, k, v, kpos, ctx);

  hipLaunchKernelGGL(moe_out_gemm, dim3(32, 8), dim3(256), 0, stream,
                     ctx, coefs, Wob, out);
}

// Round 4
// 1224.843 us; speedup vs baseline: 4.8365x; 3.0823x over previous
//
#include <hip/hip_runtime.h>
#include <hip/hip_bf16.h>
#include <math.h>

#define H_ 16
#define E_ 8
#define D_ 1024
#define P_ 64
#define PV_ 64
#define B_ 8
#define T_ 512
#define R_ 1023
#define BT_ 4096
#define CAP_ 4096

typedef __attribute__((ext_vector_type(8))) unsigned short ushort8;
typedef __attribute__((ext_vector_type(4))) unsigned short ushort4v;
typedef __attribute__((ext_vector_type(8))) short short8;
typedef __attribute__((ext_vector_type(4))) float f32x4;

__device__ inline float bf2f(unsigned short u) {
  union { unsigned int i; float f; } c; c.i = ((unsigned int)u) << 16; return c.f;
}
__device__ inline unsigned short f2bf(float f) {
  __hip_bfloat16 h = __float2bfloat16(f);
  return *reinterpret_cast<unsigned short*>(&h);
}

// ---------------------------------------------------------------- zero counts
__global__ void zero_cnt_kernel(int* __restrict__ cnt) {
  int i = threadIdx.x;
  if (i < 512) cnt[i] = 0;
}

// ---------------------------------------------------------------- gates (+x->bf16)
__global__ __launch_bounds__(128) void gates_kernel(
    const float* __restrict__ x, const float* __restrict__ wso,
    const float* __restrict__ wsv, int* __restrict__ cnt,
    int* __restrict__ lidx, float* __restrict__ lg,
    float* __restrict__ coefs, unsigned short* __restrict__ xbu) {
  __shared__ __align__(16) float xs[4][D_];
  __shared__ float gv[4][2][H_][E_];
  int tid = threadIdx.x;
  int bt0 = blockIdx.x * 4;

  const float4* xr = (const float4*)(x + (size_t)bt0 * D_);
  float4* xs4 = (float4*)xs;
  for (int i = tid; i < D_; i += 128) {
    float4 w = xr[i];
    xs4[i] = w;
    ushort4v o = {f2bf(w.x), f2bf(w.y), f2bf(w.z), f2bf(w.w)};
    *(ushort4v*)&xbu[(size_t)bt0 * D_ + i * 4] = o;
  }
  __syncthreads();

  int he = tid;
  const float4* w0 = (const float4*)(wso + (size_t)he * D_);
  const float4* w1 = (const float4*)(wsv + (size_t)he * D_);
  float a0[4] = {0.f, 0.f, 0.f, 0.f}, a1[4] = {0.f, 0.f, 0.f, 0.f};
  for (int i = 0; i < D_ / 4; i++) {
    float4 wv0 = w0[i], wv1 = w1[i];
#pragma unroll
    for (int r = 0; r < 4; r++) {
      float4 xv = ((const float4*)xs[r])[i];
      a0[r] += xv.x * wv0.x + xv.y * wv0.y + xv.z * wv0.z + xv.w * wv0.w;
      a1[r] += xv.x * wv1.x + xv.y * wv1.y + xv.z * wv1.z + xv.w * wv1.w;
    }
  }
  int h = he >> 3, e = he & 7;
#pragma unroll
  for (int r = 0; r < 4; r++) {
    gv[r][0][h][e] = 1.f / (1.f + expf(-a0[r]));
    gv[r][1][h][e] = 1.f / (1.f + expf(-a1[r]));
  }
  __syncthreads();

  {
    int r = tid >> 5, set = (tid >> 4) & 1, hh = tid & 15;
    int bt = bt0 + r;
    const float* g = gv[r][set][hh];
    int i1 = 0; float v1 = g[0];
    for (int ee = 1; ee < 8; ee++) if (g[ee] > v1) { v1 = g[ee]; i1 = ee; }
    int i2 = (i1 == 0) ? 1 : 0; float v2 = g[i2];
    for (int ee = 0; ee < 8; ee++) {
      if (ee == i1) continue;
      if (g[ee] > v2) { v2 = g[ee]; i2 = ee; }
    }
    int base1 = ((set * H_ + hh) * E_ + i1) * 2 + 0;
    int p1 = atomicAdd(&cnt[base1], 1);
    lidx[(size_t)base1 * CAP_ + p1] = bt;
    lg[(size_t)base1 * CAP_ + p1] = v1;
    int base2 = ((set * H_ + hh) * E_ + i2) * 2 + 1;
    int p2 = atomicAdd(&cnt[base2], 1);
    lidx[(size_t)base2 * CAP_ + p2] = bt;
    lg[(size_t)base2 * CAP_ + p2] = v2;
    if (set == 0) {
#pragma unroll
      for (int ee = 0; ee < 8; ee++) {
        float c = (ee == i1) ? v1 : ((ee == i2) ? v2 : 0.f);
        coefs[((size_t)bt * H_ + hh) * E_ + ee] = c;
      }
    }
  }
}

// ---------------------------------------------------------------- proj (MFMA)
// grid (128 he, 64 tiles). 64 gathered rows x 64 cols, K=1024, bf16 MFMA.
__global__ __launch_bounds__(256) void proj_mfma(
    const unsigned short* __restrict__ xb, const float* __restrict__ W,
    const int* __restrict__ cnt, const int* __restrict__ lidx,
    const float* __restrict__ lg, unsigned short* __restrict__ out,
    int set, int slot) {
  int he = blockIdx.x, tile = blockIdx.y;
  int base = (set * 128 + he) * 2 + slot;
  int n = cnt[base];
  int start = tile * 64;
  if (start >= n) return;
  int m = min(64, n - start);

  __shared__ int ridx[64];
  __shared__ float rgs[64];
  __shared__ __align__(16) unsigned short As[64][72];
  __shared__ __align__(16) unsigned short Bs[64][72];
  int tid = threadIdx.x;
  if (tid < 64) {
    int vi = 0; float g = 0.f;
    if (tid < m) {
      vi = lidx[(size_t)base * CAP_ + start + tid];
      g = lg[(size_t)base * CAP_ + start + tid];
    }
    ridx[tid] = vi; rgs[tid] = g;
  }
  __syncthreads();

  int wave = tid >> 6, lane = tid & 63;
  int lr = lane & 15, lk = (lane >> 4) << 3;
  f32x4 acc[4] = {};
  const float* Wb = W + (size_t)he * D_ * P_;

  int sr = tid >> 2, sseg = (tid & 3) << 4;  // A staging
  int bd = tid >> 6, bp = tid & 63;          // B staging

  for (int d0 = 0; d0 < D_; d0 += 64) {
    {
      const unsigned short* xrow = xb + (size_t)ridx[sr] * D_ + d0 + sseg;
      *(ushort8*)&As[sr][sseg] = *(const ushort8*)xrow;
      *(ushort8*)&As[sr][sseg + 8] = *(const ushort8*)(xrow + 8);
    }
#pragma unroll
    for (int pass = 0; pass < 16; ++pass) {
      int dr = pass * 4 + bd;
      Bs[bp][dr] = f2bf(Wb[(size_t)(d0 + dr) * P_ + bp]);
    }
    __syncthreads();
#pragma unroll
    for (int kk = 0; kk < 2; ++kk) {
      short8 af = *(const short8*)&As[wave * 16 + lr][kk * 32 + lk];
#pragma unroll
      for (int nn = 0; nn < 4; ++nn) {
        short8 bf8 = *(const short8*)&Bs[nn * 16 + lr][kk * 32 + lk];
        acc[nn] = __builtin_amdgcn_mfma_f32_16x16x32_bf16(af, bf8, acc[nn], 0, 0, 0);
      }
    }
    __syncthreads();
  }

  int h = he >> 3;
#pragma unroll
  for (int r = 0; r < 4; ++r) {
    int row = wave * 16 + (lane >> 4) * 4 + r;
    if (row < m) {
      int bt = ridx[row]; float g = rgs[row];
      int b = bt >> 9, t = bt & 511;
      unsigned short* orow = out + ((size_t)((b * H_ + h) * T_) + t) * P_;
      if (slot == 0) {
#pragma unroll
        for (int nn = 0; nn < 4; ++nn)
          orow[nn * 16 + lr] = f2bf(g * acc[nn][r]);
      } else {
#pragma unroll
        for (int nn = 0; nn < 4; ++nn) {
          int c = nn * 16 + lr;
          orow[c] = f2bf(bf2f(orow[c]) + g * acc[nn][r]);
        }
      }
    }
  }
}

// ---------------------------------------------------------------- k_pos GEMM (bf16 out)
__global__ __launch_bounds__(256) void kpos_kernel(
    const float* __restrict__ pe, const float* __restrict__ Wp,
    unsigned short* __restrict__ kposb) {
  int rt = blockIdx.x;
  int ct = blockIdx.y;
  __shared__ float ps[64][33];
  __shared__ float wsh[64][33];
  int tid = threadIdx.x;
  float acc[4][4] = {};
  int r0 = (tid >> 4) * 4, c0 = (tid & 15) * 4;
  for (int d0 = 0; d0 < D_; d0 += 32) {
    for (int i = tid; i < 64 * 32; i += 256) {
      int r = i >> 5, d = i & 31;
      int rr = rt * 64 + r;
      ps[r][d] = (rr < R_) ? pe[(size_t)rr * D_ + d0 + d] : 0.f;
    }
    for (int i = tid; i < 64 * 32; i += 256) {
      int c = i >> 5, d = i & 31;
      wsh[c][d] = Wp[(size_t)(ct * 64 + c) * D_ + d0 + d];
    }
    __syncthreads();
#pragma unroll
    for (int d = 0; d < 32; d++) {
      float pv2[4], wv[4];
#pragma unroll
      for (int i2 = 0; i2 < 4; i2++) pv2[i2] = ps[r0 + i2][d];
#pragma unroll
      for (int j = 0; j < 4; j++) wv[j] = wsh[c0 + j][d];
#pragma unroll
      for (int i2 = 0; i2 < 4; i2++)
#pragma unroll
        for (int j = 0; j < 4; j++) acc[i2][j] += pv2[i2] * wv[j];
    }
    __syncthreads();
  }
  for (int i2 = 0; i2 < 4; i2++) {
    int rr = rt * 64 + r0 + i2;
    if (rr >= R_) break;
    for (int j = 0; j < 4; j++)
      kposb[(size_t)rr * 1024 + ct * 64 + c0 + j] = f2bf(acc[i2][j]);
  }
}

// ---------------------------------------------------------------- attention (MFMA flash)
// grid (8 qtiles, 16 h, 8 b), 256 threads = 4 waves; wave w owns q-rows w*16..w*16+15.
__global__ __launch_bounds__(256) void attn_mfma(
    const unsigned short* __restrict__ q, const unsigned short* __restrict__ k,
    const unsigned short* __restrict__ v, const unsigned short* __restrict__ kposb,
    unsigned short* __restrict__ ctx) {
  int qt = blockIdx.x, h = blockIdx.y, b = blockIdx.z;
  int t0 = qt << 6;
  int tid = threadIdx.x, wave = tid >> 6, lane = tid & 63;
  int lr = lane & 15, lkg = lane >> 4;
  int lk = lkg << 3;

  __shared__ __align__(16) unsigned short Ks[64][72];
  __shared__ __align__(16) unsigned short VTs[64][72];
  __shared__ __align__(16) unsigned short Srl[64][136];  // cols 0..127 Srel; 64..127 reused as P

  size_t bh = (size_t)(b * H_ + h);
  const unsigned short* kb = k + bh * T_ * 64;
  const unsigned short* vb = v + bh * T_ * 64;
  const unsigned short* qb = q + bh * T_ * 64;

  short8 qf[2];
  {
    const unsigned short* qrow = qb + (size_t)(t0 + wave * 16 + lr) * 64;
    qf[0] = *(const short8*)&qrow[lk];
    qf[1] = *(const short8*)&qrow[32 + lk];
  }

  float m_run[4], l_run[4];
  f32x4 oacc[4];
#pragma unroll
  for (int r = 0; r < 4; ++r) { m_run[r] = -1e30f; l_run[r] = 0.f; }
#pragma unroll
  for (int nn = 0; nn < 4; ++nn) oacc[nn] = (f32x4){0.f, 0.f, 0.f, 0.f};

  int row_local = wave * 16 + lkg * 4;  // + reg

  int sstg = tid >> 2, sseg = (tid & 3) << 4;  // staging decomposition

  for (int st = 0; st <= qt; ++st) {
    int s0 = st << 6;
    // stage K rows + V^T
    {
      const unsigned short* krow = kb + (size_t)(s0 + sstg) * 64 + sseg;
      *(ushort8*)&Ks[sstg][sseg] = *(const ushort8*)krow;
      *(ushort8*)&Ks[sstg][sseg + 8] = *(const ushort8*)(krow + 8);
      const unsigned short* vrow = vb + (size_t)(s0 + sstg) * 64 + sseg;
      ushort8 v0 = *(const ushort8*)vrow, v1 = *(const ushort8*)(vrow + 8);
#pragma unroll
      for (int j = 0; j < 8; ++j) VTs[sseg + j][sstg] = v0[j];
#pragma unroll
      for (int j = 0; j < 8; ++j) VTs[sseg + 8 + j][sstg] = v1[j];
    }
    __syncthreads();

    // content scores: wave's 16 q-rows x 64 s-cols
    f32x4 sc[4] = {};
#pragma unroll
    for (int kk = 0; kk < 2; ++kk) {
#pragma unroll
      for (int nn = 0; nn < 4; ++nn) {
        short8 bfk = *(const short8*)&Ks[nn * 16 + lr][kk * 32 + lk];
        sc[nn] = __builtin_amdgcn_mfma_f32_16x16x32_bf16(qf[kk], bfk, sc[nn], 0, 0, 0);
      }
    }
    // rel scores: 64 q-rows x 128 band cols, B-frags direct from global kposb
    int r_base = s0 - t0 + 448;
    const unsigned short* kpb = kposb + (size_t)r_base * 1024 + h * 64;
    f32x4 srf[8] = {};
#pragma unroll
    for (int kk = 0; kk < 2; ++kk) {
#pragma unroll
      for (int nn = 0; nn < 8; ++nn) {
        short8 bfp = *(const short8*)&kpb[(size_t)(nn * 16 + lr) * 1024 + kk * 32 + lk];
        srf[nn] = __builtin_amdgcn_mfma_f32_16x16x32_bf16(qf[kk], bfp, srf[nn], 0, 0, 0);
      }
    }
    // store Srel (wave-local rows)
#pragma unroll
    for (int nn = 0; nn < 8; ++nn)
#pragma unroll
      for (int r = 0; r < 4; ++r)
        Srl[row_local + r][nn * 16 + lr] = f2bf(srf[nn][r]);

    // gather + mask
    float sv[4][4];
#pragma unroll
    for (int nn = 0; nn < 4; ++nn) {
#pragma unroll
      for (int r = 0; r < 4; ++r) {
        int row = row_local + r;
        int scc = nn * 16 + lr;
        int rj = scc - row + 63;
        float spos = bf2f(Srl[row][rj]);
        float sval = (sc[nn][r] + spos) * 0.125f;
        sv[nn][r] = ((s0 + scc) <= (t0 + row)) ? sval : -1e9f;
      }
    }
    // online softmax update (rows spread over 16-lane groups)
    float alpha[4];
#pragma unroll
    for (int r = 0; r < 4; ++r) {
      float mx = fmaxf(fmaxf(sv[0][r], sv[1][r]), fmaxf(sv[2][r], sv[3][r]));
      mx = fmaxf(mx, __shfl_xor(mx, 1));
      mx = fmaxf(mx, __shfl_xor(mx, 2));
      mx = fmaxf(mx, __shfl_xor(mx, 4));
      mx = fmaxf(mx, __shfl_xor(mx, 8));
      float mn = fmaxf(m_run[r], mx);
      alpha[r] = __expf(m_run[r] - mn);
      m_run[r] = mn;
    }
    float psum[4] = {0.f, 0.f, 0.f, 0.f};
#pragma unroll
    for (int nn = 0; nn < 4; ++nn) {
#pragma unroll
      for (int r = 0; r < 4; ++r) {
        unsigned short pb = f2bf(__expf(sv[nn][r] - m_run[r]));
        Srl[row_local + r][64 + nn * 16 + lr] = pb;  // P region (cols 64..127)
        psum[r] += bf2f(pb);
      }
    }
#pragma unroll
    for (int r = 0; r < 4; ++r) {
      float s = psum[r];
      s += __shfl_xor(s, 1); s += __shfl_xor(s, 2);
      s += __shfl_xor(s, 4); s += __shfl_xor(s, 8);
      l_run[r] = l_run[r] * alpha[r] + s;
#pragma unroll
      for (int nn = 0; nn < 4; ++nn) oacc[nn][r] *= alpha[r];
    }
    // PV
#pragma unroll
    for (int kk = 0; kk < 2; ++kk) {
      short8 pa = *(const short8*)&Srl[wave * 16 + lr][64 + kk * 32 + lk];
#pragma unroll
      for (int nn = 0; nn < 4; ++nn) {
        short8 bv = *(const short8*)&VTs[nn * 16 + lr][kk * 32 + lk];
        oacc[nn] = __builtin_amdgcn_mfma_f32_16x16x32_bf16(pa, bv, oacc[nn], 0, 0, 0);
      }
    }
    __syncthreads();
  }

#pragma unroll
  for (int r = 0; r < 4; ++r) {
    float inv = 1.f / l_run[r];
    int tg = t0 + row_local + r;
    unsigned short* crow = ctx + ((size_t)(b * T_ + tg) * H_ + h) * PV_;
#pragma unroll
    for (int nn = 0; nn < 4; ++nn)
      crow[nn * 16 + lr] = f2bf(oacc[nn][r] * inv);
  }
}

// ---------------------------------------------------------------- Wo transpose
__global__ __launch_bounds__(256) void wo_transpose_kernel(
    const float* __restrict__ Wo, __hip_bfloat16* __restrict__ Wob) {
  __shared__ float t[64][65];
  int kt = blockIdx.x, dt = blockIdx.y;
  int tid = threadIdx.x;
  int kr = tid >> 2, dseg = (tid & 3) * 16;
  const float4* src = (const float4*)&Wo[(size_t)(kt * 64 + kr) * 1024 + dt * 64 + dseg];
#pragma unroll
  for (int i = 0; i < 4; ++i) {
    float4 v4 = src[i];
    t[kr][dseg + i * 4 + 0] = v4.x;
    t[kr][dseg + i * 4 + 1] = v4.y;
    t[kr][dseg + i * 4 + 2] = v4.z;
    t[kr][dseg + i * 4 + 3] = v4.w;
  }
  __syncthreads();
  int dr = tid >> 2, kseg = (tid & 3) * 16;
  unsigned short* dst =
      (unsigned short*)Wob + (size_t)(dt * 64 + dr) * 8192 + kt * 64 + kseg;
#pragma unroll
  for (int half = 0; half < 2; ++half) {
    ushort8 o;
#pragma unroll
    for (int j = 0; j < 8; ++j) o[j] = f2bf(t[kseg + half * 8 + j][dr]);
    *(ushort8*)&dst[half * 8] = o;
  }
}

// ---------------------------------------------------------------- MoE out GEMM
__global__ __launch_bounds__(256) void moe_out_gemm(
    const __hip_bfloat16* __restrict__ ctx, const float* __restrict__ coefs,
    const __hip_bfloat16* __restrict__ Wob, float* __restrict__ out) {
  __shared__ __align__(16) unsigned short As[128][72];
  __shared__ __align__(16) unsigned short Bs[128][72];
  int tid = threadIdx.x;
  int mt = blockIdx.x, nt = blockIdx.y;
  int wave = tid >> 6, lane = tid & 63;
  int wr = wave >> 1, wc = wave & 1;
  int lrow = lane & 15, lk = (lane >> 4) << 3;

  f32x4 acc[4][4] = {};

  int arow = tid >> 1;
  int aseg = (tid & 1) * 32;
  const unsigned short* ctxu = (const unsigned short*)ctx;
  const unsigned short* wobu = (const unsigned short*)Wob;
  size_t grow = (size_t)mt * 128 + arow;

  for (int he = 0; he < 128; ++he) {
    int h = he >> 3;
    float cf = coefs[grow * 128 + he];
    const ushort8* asrc = (const ushort8*)&ctxu[(grow * 16 + h) * 64 + aseg];
    const ushort8* bsrc =
        (const ushort8*)&wobu[((size_t)nt * 128 + arow) * 8192 + he * 64 + aseg];
#pragma unroll
    for (int i = 0; i < 4; ++i) {
      ushort8 u = asrc[i];
      ushort8 o;
#pragma unroll
      for (int j = 0; j < 8; ++j) o[j] = f2bf(bf2f(u[j]) * cf);
      *(ushort8*)&As[arow][aseg + i * 8] = o;
      *(ushort8*)&Bs[arow][aseg + i * 8] = bsrc[i];
    }
    __syncthreads();
#pragma unroll
    for (int kk = 0; kk < 2; ++kk) {
      short8 af[4], bfr[4];
#pragma unroll
      for (int m = 0; m < 4; ++m)
        af[m] = *(const short8*)&As[wr * 64 + m * 16 + lrow][kk * 32 + lk];
#pragma unroll
      for (int n = 0; n < 4; ++n)
        bfr[n] = *(const short8*)&Bs[wc * 64 + n * 16 + lrow][kk * 32 + lk];
#pragma unroll
      for (int m = 0; m < 4; ++m)
#pragma unroll
        for (int n = 0; n < 4; ++n)
          acc[m][n] = __builtin_amdgcn_mfma_f32_16x16x32_bf16(
              af[m], bfr[n], acc[m][n], 0, 0, 0);
    }
    __syncthreads();
  }

  int orow0 = mt * 128 + wr * 64 + (lane >> 4) * 4;
  int ocol0 = nt * 128 + wc * 64 + lrow;
#pragma unroll
  for (int m = 0; m < 4; ++m)
#pragma unroll
    for (int n = 0; n < 4; ++n)
#pragma unroll
      for (int r = 0; r < 4; ++r)
        out[(size_t)(orow0 + m * 16 + r) * 1024 + ocol0 + n * 16] = acc[m][n][r];
}

// ---------------------------------------------------------------- launch
extern "C" void kernel_launch(void* const* d_in, const int* in_sizes, int n_in,
                              void* d_out, int out_size, void* d_ws, size_t ws_size,
                              hipStream_t stream) {
  const float* x   = (const float*)d_in[0];
  const float* pe  = (const float*)d_in[1];
  const float* wso = (const float*)d_in[2];
  const float* wsv = (const float*)d_in[3];
  const float* Wq  = (const float*)d_in[4];
  const float* Wk  = (const float*)d_in[5];
  const float* Wv  = (const float*)d_in[6];
  const float* Wo  = (const float*)d_in[7];
  const float* Wp  = (const float*)d_in[8];
  float* out = (float*)d_out;
  char* ws = (char*)d_ws;

  // workspace carve-up (bytes), total 54,528,000 (< proven 55.6 MB)
  int*   cnt   = (int*)  (ws + 0);
  float* coefs = (float*)(ws + 4096);                       // 2 MiB
  int*   lidx  = (int*)  (ws + 2101248);                    // 8 MiB
  float* lg    = (float*)(ws + 10489856);                   // 8 MiB
  unsigned short* xb    = (unsigned short*)(ws + 18878464); // 8 MiB
  unsigned short* kposb = (unsigned short*)(ws + 27267072); // 2 MiB (1023x1024 bf16)
  unsigned short* q     = (unsigned short*)(ws + 29362176); // 8 MiB (b,h,t,p)
  unsigned short* k     = (unsigned short*)(ws + 37750784); // 8 MiB
  unsigned short* v     = (unsigned short*)(ws + 46139392); // 8 MiB
  // aliases (dead-region reuse after projections):
  __hip_bfloat16* ctx = (__hip_bfloat16*)(ws + 2101248);    // 8 MiB over lidx
  __hip_bfloat16* Wob = (__hip_bfloat16*)(ws + 10489856);   // 16 MiB over lg+xb

  hipLaunchKernelGGL(zero_cnt_kernel, dim3(1), dim3(512), 0, stream, cnt);
  hipLaunchKernelGGL(gates_kernel, dim3(BT_ / 4), dim3(128), 0, stream,
                     x, wso, wsv, cnt, lidx, lg, coefs, xb);
  hipLaunchKernelGGL(kpos_kernel, dim3(16, 16), dim3(256), 0, stream, pe, Wp, kposb);

  hipLaunchKernelGGL(proj_mfma, dim3(128, 64), dim3(256), 0, stream,
                     xb, Wq, cnt, lidx, lg, q, 0, 0);
  hipLaunchKernelGGL(proj_mfma, dim3(128, 64), dim3(256), 0, stream,
                     xb, Wq, cnt, lidx, lg, q, 0, 1);
  hipLaunchKernelGGL(proj_mfma, dim3(128, 64), dim3(256), 0, stream,
                     xb, Wk, cnt, lidx, lg, k, 1, 0);
  hipLaunchKernelGGL(proj_mfma, dim3(128, 64), dim3(256), 0, stream,
                     xb, Wk, cnt, lidx, lg, k, 1, 1);
  hipLaunchKernelGGL(proj_mfma, dim3(128, 64), dim3(256), 0, stream,
                     xb, Wv, cnt, lidx, lg, v, 1, 0);
  hipLaunchKernelGGL(proj_mfma, dim3(128, 64), dim3(256), 0, stream,
                     xb, Wv, cnt, lidx, lg, v, 1, 1);

  // lg+xb dead after projections: overwrite with Wob (bf16 [d][k]).
  hipLaunchKernelGGL(wo_transpose_kernel, dim3(128, 16), dim3(256), 0, stream,
                     Wo, (__hip_bfloat16*)Wob);

  hipLaunchKernelGGL(attn_mfma, dim3(8, 16, 8), dim3(256), 0, stream,
                     q, k, v, kposb, (unsigned short*)ctx);

  hipLaunchKernelGGL(moe_out_gemm, dim3(32, 8), dim3(256), 0, stream,
                     ctx, coefs, Wob, out);
}

// Round 5
// 880.979 us; speedup vs baseline: 6.7243x; 1.3903x over previous
//
#include <hip/hip_runtime.h>
#include <hip/hip_bf16.h>
#include <math.h>

#define H_ 16
#define E_ 8
#define D_ 1024
#define P_ 64
#define PV_ 64
#define B_ 8
#define T_ 512
#define R_ 1023
#define BT_ 4096
#define CAP_ 4096

typedef __attribute__((ext_vector_type(8))) unsigned short ushort8;
typedef __attribute__((ext_vector_type(4))) unsigned short ushort4v;
typedef __attribute__((ext_vector_type(8))) short short8;
typedef __attribute__((ext_vector_type(4))) float f32x4;

__device__ inline float bf2f(unsigned short u) {
  union { unsigned int i; float f; } c; c.i = ((unsigned int)u) << 16; return c.f;
}
__device__ inline unsigned short f2bf(float f) {
  __hip_bfloat16 h = __float2bfloat16(f);
  return *reinterpret_cast<unsigned short*>(&h);
}

// ---------------------------------------------------------------- zero counts
__global__ void zero_cnt_kernel(int* __restrict__ cnt) {
  int i = threadIdx.x;
  if (i < 512) cnt[i] = 0;
}

// ---------------------------------------------------------------- gates (+x->bf16)
// 256 threads, 8 bt rows/block. Thread owns one (set,he); LDS x reads broadcast.
__global__ __launch_bounds__(256) void gates_kernel(
    const float* __restrict__ x, const float* __restrict__ wso,
    const float* __restrict__ wsv, int* __restrict__ cnt,
    int* __restrict__ lidx, float* __restrict__ lg,
    float* __restrict__ coefs, unsigned short* __restrict__ xbu) {
  __shared__ __align__(16) float xs[8][D_];     // 32 KB
  __shared__ float gv[8][2][H_][E_];            // 8 KB
  int tid = threadIdx.x;
  int bt0 = blockIdx.x * 8;

  const float4* xr = (const float4*)(x + (size_t)bt0 * D_);
  float4* xs4 = (float4*)xs;
  for (int i = tid; i < 2048; i += 256) {
    float4 w = xr[i];
    xs4[i] = w;
    ushort4v o = {f2bf(w.x), f2bf(w.y), f2bf(w.z), f2bf(w.w)};
    *(ushort4v*)&xbu[(size_t)bt0 * D_ + i * 4] = o;
  }
  __syncthreads();

  int set = tid >> 7, he = tid & 127;
  const float4* w4 = (const float4*)((set ? wsv : wso) + (size_t)he * D_);
  float acc[8] = {};
#pragma unroll 2
  for (int i = 0; i < 256; ++i) {
    float4 wv = w4[i];
#pragma unroll
    for (int r = 0; r < 8; ++r) {
      float4 xv = ((const float4*)xs[r])[i];
      acc[r] += xv.x * wv.x + xv.y * wv.y + xv.z * wv.z + xv.w * wv.w;
    }
  }
  int h = he >> 3, e = he & 7;
#pragma unroll
  for (int r = 0; r < 8; ++r)
    gv[r][set][h][e] = 1.f / (1.f + expf(-acc[r]));
  __syncthreads();

  // 256 threads = 8 rows x 2 sets x 16 heads : top-2 per (row,set,h)
  {
    int r = tid >> 5, st = (tid >> 4) & 1, hh = tid & 15;
    int bt = bt0 + r;
    const float* g = gv[r][st][hh];
    int i1 = 0; float v1 = g[0];
    for (int ee = 1; ee < 8; ee++) if (g[ee] > v1) { v1 = g[ee]; i1 = ee; }
    int i2 = (i1 == 0) ? 1 : 0; float v2 = g[i2];
    for (int ee = 0; ee < 8; ee++) {
      if (ee == i1) continue;
      if (g[ee] > v2) { v2 = g[ee]; i2 = ee; }
    }
    int base1 = ((st * H_ + hh) * E_ + i1) * 2 + 0;
    int p1 = atomicAdd(&cnt[base1], 1);
    lidx[(size_t)base1 * CAP_ + p1] = bt;
    lg[(size_t)base1 * CAP_ + p1] = v1;
    int base2 = ((st * H_ + hh) * E_ + i2) * 2 + 1;
    int p2 = atomicAdd(&cnt[base2], 1);
    lidx[(size_t)base2 * CAP_ + p2] = bt;
    lg[(size_t)base2 * CAP_ + p2] = v2;
    if (st == 0) {
#pragma unroll
      for (int ee = 0; ee < 8; ee++) {
        float c = (ee == i1) ? v1 : ((ee == i2) ? v2 : 0.f);
        coefs[((size_t)bt * H_ + hh) * E_ + ee] = c;
      }
    }
  }
}

// ---------------------------------------------------------------- proj (MFMA)
__global__ __launch_bounds__(256) void proj_mfma(
    const unsigned short* __restrict__ xb, const float* __restrict__ W,
    const int* __restrict__ cnt, const int* __restrict__ lidx,
    const float* __restrict__ lg, unsigned short* __restrict__ out,
    int set, int slot) {
  int he = blockIdx.x, tile = blockIdx.y;
  int base = (set * 128 + he) * 2 + slot;
  int n = cnt[base];
  int start = tile * 64;
  if (start >= n) return;
  int m = min(64, n - start);

  __shared__ int ridx[64];
  __shared__ float rgs[64];
  __shared__ __align__(16) unsigned short As[64][72];
  __shared__ __align__(16) unsigned short Bs[64][72];
  int tid = threadIdx.x;
  if (tid < 64) {
    int vi = 0; float g = 0.f;
    if (tid < m) {
      vi = lidx[(size_t)base * CAP_ + start + tid];
      g = lg[(size_t)base * CAP_ + start + tid];
    }
    ridx[tid] = vi; rgs[tid] = g;
  }
  __syncthreads();

  int wave = tid >> 6, lane = tid & 63;
  int lr = lane & 15, lk = (lane >> 4) << 3;
  f32x4 acc[4] = {};
  const float* Wb = W + (size_t)he * D_ * P_;

  int sr = tid >> 2, sseg = (tid & 3) << 4;  // A staging
  int c4 = (tid & 15) * 4;                   // B staging: float4 + transpose
  int drb = tid >> 4;

  for (int d0 = 0; d0 < D_; d0 += 64) {
    {
      const unsigned short* xrow = xb + (size_t)ridx[sr] * D_ + d0 + sseg;
      *(ushort8*)&As[sr][sseg] = *(const ushort8*)xrow;
      *(ushort8*)&As[sr][sseg + 8] = *(const ushort8*)(xrow + 8);
    }
#pragma unroll
    for (int pass = 0; pass < 4; ++pass) {
      int dr = pass * 16 + drb;
      float4 wv = *(const float4*)&Wb[(size_t)(d0 + dr) * P_ + c4];
      Bs[c4 + 0][dr] = f2bf(wv.x);
      Bs[c4 + 1][dr] = f2bf(wv.y);
      Bs[c4 + 2][dr] = f2bf(wv.z);
      Bs[c4 + 3][dr] = f2bf(wv.w);
    }
    __syncthreads();
#pragma unroll
    for (int kk = 0; kk < 2; ++kk) {
      short8 af = *(const short8*)&As[wave * 16 + lr][kk * 32 + lk];
#pragma unroll
      for (int nn = 0; nn < 4; ++nn) {
        short8 bf8 = *(const short8*)&Bs[nn * 16 + lr][kk * 32 + lk];
        acc[nn] = __builtin_amdgcn_mfma_f32_16x16x32_bf16(af, bf8, acc[nn], 0, 0, 0);
      }
    }
    __syncthreads();
  }

  int h = he >> 3;
#pragma unroll
  for (int r = 0; r < 4; ++r) {
    int row = wave * 16 + (lane >> 4) * 4 + r;
    if (row < m) {
      int bt = ridx[row]; float g = rgs[row];
      int b = bt >> 9, t = bt & 511;
      unsigned short* orow = out + ((size_t)((b * H_ + h) * T_) + t) * P_;
      if (slot == 0) {
#pragma unroll
        for (int nn = 0; nn < 4; ++nn)
          orow[nn * 16 + lr] = f2bf(g * acc[nn][r]);
      } else {
#pragma unroll
        for (int nn = 0; nn < 4; ++nn) {
          int c = nn * 16 + lr;
          orow[c] = f2bf(bf2f(orow[c]) + g * acc[nn][r]);
        }
      }
    }
  }
}

// ---------------------------------------------------------------- pe/Wpos -> bf16
__global__ __launch_bounds__(256) void cvt_pos_kernel(
    const float* __restrict__ pe, const float* __restrict__ Wp,
    unsigned short* __restrict__ peb, unsigned short* __restrict__ wpb) {
  int bid = blockIdx.x;  // 0..2046
  const float* src;
  unsigned short* dst;
  if (bid < R_) { src = pe + (size_t)bid * D_; dst = peb + (size_t)bid * D_; }
  else { src = Wp + (size_t)(bid - R_) * D_; dst = wpb + (size_t)(bid - R_) * D_; }
  int tid = threadIdx.x;
  float4 w = ((const float4*)src)[tid];
  ushort4v o = {f2bf(w.x), f2bf(w.y), f2bf(w.z), f2bf(w.w)};
  *(ushort4v*)&dst[tid * 4] = o;
}

// ---------------------------------------------------------------- k_pos MFMA
// kposb[r][hp] = sum_d peb[r][d] * wpb[hp][d]; only rows < 640 needed (causal).
__global__ __launch_bounds__(256) void kpos_mfma(
    const unsigned short* __restrict__ peb, const unsigned short* __restrict__ wpb,
    unsigned short* __restrict__ kposb) {
  __shared__ __align__(16) unsigned short As[128][72];
  __shared__ __align__(16) unsigned short Bs[128][72];
  int tid = threadIdx.x, mt = blockIdx.x, nt = blockIdx.y;
  int wave = tid >> 6, lane = tid & 63;
  int wr = wave >> 1, wc = wave & 1;
  int lrow = lane & 15, lk = (lane >> 4) << 3;
  f32x4 acc[4][4] = {};
  int arow = tid >> 1, aseg = (tid & 1) * 32;

  for (int d0 = 0; d0 < D_; d0 += 64) {
    const ushort8* asrc = (const ushort8*)&peb[((size_t)mt * 128 + arow) * D_ + d0 + aseg];
    const ushort8* bsrc = (const ushort8*)&wpb[((size_t)nt * 128 + arow) * D_ + d0 + aseg];
#pragma unroll
    for (int i = 0; i < 4; ++i) {
      *(ushort8*)&As[arow][aseg + i * 8] = asrc[i];
      *(ushort8*)&Bs[arow][aseg + i * 8] = bsrc[i];
    }
    __syncthreads();
#pragma unroll
    for (int kk = 0; kk < 2; ++kk) {
      short8 af[4], bfr[4];
#pragma unroll
      for (int m = 0; m < 4; ++m)
        af[m] = *(const short8*)&As[wr * 64 + m * 16 + lrow][kk * 32 + lk];
#pragma unroll
      for (int n = 0; n < 4; ++n)
        bfr[n] = *(const short8*)&Bs[wc * 64 + n * 16 + lrow][kk * 32 + lk];
#pragma unroll
      for (int m = 0; m < 4; ++m)
#pragma unroll
        for (int n = 0; n < 4; ++n)
          acc[m][n] = __builtin_amdgcn_mfma_f32_16x16x32_bf16(
              af[m], bfr[n], acc[m][n], 0, 0, 0);
    }
    __syncthreads();
  }

  int orow0 = mt * 128 + wr * 64 + (lane >> 4) * 4;
  int ocol0 = nt * 128 + wc * 64 + lrow;
#pragma unroll
  for (int m = 0; m < 4; ++m)
#pragma unroll
    for (int n = 0; n < 4; ++n)
#pragma unroll
      for (int r = 0; r < 4; ++r)
        kposb[(size_t)(orow0 + m * 16 + r) * 1024 + ocol0 + n * 16] =
            f2bf(acc[m][n][r]);
}

// ---------------------------------------------------------------- attention (MFMA flash)
__global__ __launch_bounds__(256) void attn_mfma(
    const unsigned short* __restrict__ q, const unsigned short* __restrict__ k,
    const unsigned short* __restrict__ v, const unsigned short* __restrict__ kposb,
    unsigned short* __restrict__ ctx) {
  int qt = blockIdx.x, h = blockIdx.y, b = blockIdx.z;
  int t0 = qt << 6;
  int tid = threadIdx.x, wave = tid >> 6, lane = tid & 63;
  int lr = lane & 15, lkg = lane >> 4;
  int lk = lkg << 3;

  __shared__ __align__(16) unsigned short Ks[64][72];
  __shared__ __align__(16) unsigned short VTs[64][72];
  __shared__ __align__(16) unsigned short Srl[64][136];

  size_t bh = (size_t)(b * H_ + h);
  const unsigned short* kb = k + bh * T_ * 64;
  const unsigned short* vb = v + bh * T_ * 64;
  const unsigned short* qb = q + bh * T_ * 64;

  short8 qf[2];
  {
    const unsigned short* qrow = qb + (size_t)(t0 + wave * 16 + lr) * 64;
    qf[0] = *(const short8*)&qrow[lk];
    qf[1] = *(const short8*)&qrow[32 + lk];
  }

  float m_run[4], l_run[4];
  f32x4 oacc[4];
#pragma unroll
  for (int r = 0; r < 4; ++r) { m_run[r] = -1e30f; l_run[r] = 0.f; }
#pragma unroll
  for (int nn = 0; nn < 4; ++nn) oacc[nn] = (f32x4){0.f, 0.f, 0.f, 0.f};

  int row_local = wave * 16 + lkg * 4;
  int sstg = tid >> 2, sseg = (tid & 3) << 4;

  for (int st = 0; st <= qt; ++st) {
    int s0 = st << 6;
    {
      const unsigned short* krow = kb + (size_t)(s0 + sstg) * 64 + sseg;
      *(ushort8*)&Ks[sstg][sseg] = *(const ushort8*)krow;
      *(ushort8*)&Ks[sstg][sseg + 8] = *(const ushort8*)(krow + 8);
      const unsigned short* vrow = vb + (size_t)(s0 + sstg) * 64 + sseg;
      ushort8 v0 = *(const ushort8*)vrow, v1 = *(const ushort8*)(vrow + 8);
#pragma unroll
      for (int j = 0; j < 8; ++j) VTs[sseg + j][sstg] = v0[j];
#pragma unroll
      for (int j = 0; j < 8; ++j) VTs[sseg + 8 + j][sstg] = v1[j];
    }
    __syncthreads();

    f32x4 sc[4] = {};
#pragma unroll
    for (int kk = 0; kk < 2; ++kk) {
#pragma unroll
      for (int nn = 0; nn < 4; ++nn) {
        short8 bfk = *(const short8*)&Ks[nn * 16 + lr][kk * 32 + lk];
        sc[nn] = __builtin_amdgcn_mfma_f32_16x16x32_bf16(qf[kk], bfk, sc[nn], 0, 0, 0);
      }
    }
    int r_base = s0 - t0 + 448;
    const unsigned short* kpb = kposb + (size_t)r_base * 1024 + h * 64;
    f32x4 srf[8] = {};
#pragma unroll
    for (int kk = 0; kk < 2; ++kk) {
#pragma unroll
      for (int nn = 0; nn < 8; ++nn) {
        short8 bfp = *(const short8*)&kpb[(size_t)(nn * 16 + lr) * 1024 + kk * 32 + lk];
        srf[nn] = __builtin_amdgcn_mfma_f32_16x16x32_bf16(qf[kk], bfp, srf[nn], 0, 0, 0);
      }
    }
#pragma unroll
    for (int nn = 0; nn < 8; ++nn)
#pragma unroll
      for (int r = 0; r < 4; ++r)
        Srl[row_local + r][nn * 16 + lr] = f2bf(srf[nn][r]);

    float sv[4][4];
#pragma unroll
    for (int nn = 0; nn < 4; ++nn) {
#pragma unroll
      for (int r = 0; r < 4; ++r) {
        int row = row_local + r;
        int scc = nn * 16 + lr;
        int rj = scc - row + 63;
        float spos = bf2f(Srl[row][rj]);
        float sval = (sc[nn][r] + spos) * 0.125f;
        sv[nn][r] = ((s0 + scc) <= (t0 + row)) ? sval : -1e9f;
      }
    }
    float alpha[4];
#pragma unroll
    for (int r = 0; r < 4; ++r) {
      float mx = fmaxf(fmaxf(sv[0][r], sv[1][r]), fmaxf(sv[2][r], sv[3][r]));
      mx = fmaxf(mx, __shfl_xor(mx, 1));
      mx = fmaxf(mx, __shfl_xor(mx, 2));
      mx = fmaxf(mx, __shfl_xor(mx, 4));
      mx = fmaxf(mx, __shfl_xor(mx, 8));
      float mn = fmaxf(m_run[r], mx);
      alpha[r] = __expf(m_run[r] - mn);
      m_run[r] = mn;
    }
    float psum[4] = {0.f, 0.f, 0.f, 0.f};
#pragma unroll
    for (int nn = 0; nn < 4; ++nn) {
#pragma unroll
      for (int r = 0; r < 4; ++r) {
        unsigned short pb = f2bf(__expf(sv[nn][r] - m_run[r]));
        Srl[row_local + r][64 + nn * 16 + lr] = pb;
        psum[r] += bf2f(pb);
      }
    }
#pragma unroll
    for (int r = 0; r < 4; ++r) {
      float s = psum[r];
      s += __shfl_xor(s, 1); s += __shfl_xor(s, 2);
      s += __shfl_xor(s, 4); s += __shfl_xor(s, 8);
      l_run[r] = l_run[r] * alpha[r] + s;
#pragma unroll
      for (int nn = 0; nn < 4; ++nn) oacc[nn][r] *= alpha[r];
    }
#pragma unroll
    for (int kk = 0; kk < 2; ++kk) {
      short8 pa = *(const short8*)&Srl[wave * 16 + lr][64 + kk * 32 + lk];
#pragma unroll
      for (int nn = 0; nn < 4; ++nn) {
        short8 bv = *(const short8*)&VTs[nn * 16 + lr][kk * 32 + lk];
        oacc[nn] = __builtin_amdgcn_mfma_f32_16x16x32_bf16(pa, bv, oacc[nn], 0, 0, 0);
      }
    }
    __syncthreads();
  }

#pragma unroll
  for (int r = 0; r < 4; ++r) {
    float inv = 1.f / l_run[r];
    int tg = t0 + row_local + r;
    unsigned short* crow = ctx + ((size_t)(b * T_ + tg) * H_ + h) * PV_;
#pragma unroll
    for (int nn = 0; nn < 4; ++nn)
      crow[nn * 16 + lr] = f2bf(oacc[nn][r] * inv);
  }
}

// ---------------------------------------------------------------- Wo transpose
__global__ __launch_bounds__(256) void wo_transpose_kernel(
    const float* __restrict__ Wo, __hip_bfloat16* __restrict__ Wob) {
  __shared__ float t[64][65];
  int kt = blockIdx.x, dt = blockIdx.y;
  int tid = threadIdx.x;
  int kr = tid >> 2, dseg = (tid & 3) * 16;
  const float4* src = (const float4*)&Wo[(size_t)(kt * 64 + kr) * 1024 + dt * 64 + dseg];
#pragma unroll
  for (int i = 0; i < 4; ++i) {
    float4 v4 = src[i];
    t[kr][dseg + i * 4 + 0] = v4.x;
    t[kr][dseg + i * 4 + 1] = v4.y;
    t[kr][dseg + i * 4 + 2] = v4.z;
    t[kr][dseg + i * 4 + 3] = v4.w;
  }
  __syncthreads();
  int dr = tid >> 2, kseg = (tid & 3) * 16;
  unsigned short* dst =
      (unsigned short*)Wob + (size_t)(dt * 64 + dr) * 8192 + kt * 64 + kseg;
#pragma unroll
  for (int half = 0; half < 2; ++half) {
    ushort8 o;
#pragma unroll
    for (int j = 0; j < 8; ++j) o[j] = f2bf(t[kseg + half * 8 + j][dr]);
    *(ushort8*)&dst[half * 8] = o;
  }
}

// ---------------------------------------------------------------- MoE out GEMM
__global__ __launch_bounds__(256) void moe_out_gemm(
    const __hip_bfloat16* __restrict__ ctx, const float* __restrict__ coefs,
    const __hip_bfloat16* __restrict__ Wob, float* __restrict__ out) {
  __shared__ __align__(16) unsigned short As[128][72];
  __shared__ __align__(16) unsigned short Bs[128][72];
  int tid = threadIdx.x;
  int mt = blockIdx.x, nt = blockIdx.y;
  int wave = tid >> 6, lane = tid & 63;
  int wr = wave >> 1, wc = wave & 1;
  int lrow = lane & 15, lk = (lane >> 4) << 3;

  f32x4 acc[4][4] = {};

  int arow = tid >> 1;
  int aseg = (tid & 1) * 32;
  const unsigned short* ctxu = (const unsigned short*)ctx;
  const unsigned short* wobu = (const unsigned short*)Wob;
  size_t grow = (size_t)mt * 128 + arow;

  for (int he = 0; he < 128; ++he) {
    int h = he >> 3;
    float cf = coefs[grow * 128 + he];
    const ushort8* asrc = (const ushort8*)&ctxu[(grow * 16 + h) * 64 + aseg];
    const ushort8* bsrc =
        (const ushort8*)&wobu[((size_t)nt * 128 + arow) * 8192 + he * 64 + aseg];
#pragma unroll
    for (int i = 0; i < 4; ++i) {
      ushort8 u = asrc[i];
      ushort8 o;
#pragma unroll
      for (int j = 0; j < 8; ++j) o[j] = f2bf(bf2f(u[j]) * cf);
      *(ushort8*)&As[arow][aseg + i * 8] = o;
      *(ushort8*)&Bs[arow][aseg + i * 8] = bsrc[i];
    }
    __syncthreads();
#pragma unroll
    for (int kk = 0; kk < 2; ++kk) {
      short8 af[4], bfr[4];
#pragma unroll
      for (int m = 0; m < 4; ++m)
        af[m] = *(const short8*)&As[wr * 64 + m * 16 + lrow][kk * 32 + lk];
#pragma unroll
      for (int n = 0; n < 4; ++n)
        bfr[n] = *(const short8*)&Bs[wc * 64 + n * 16 + lrow][kk * 32 + lk];
#pragma unroll
      for (int m = 0; m < 4; ++m)
#pragma unroll
        for (int n = 0; n < 4; ++n)
          acc[m][n] = __builtin_amdgcn_mfma_f32_16x16x32_bf16(
              af[m], bfr[n], acc[m][n], 0, 0, 0);
    }
    __syncthreads();
  }

  int orow0 = mt * 128 + wr * 64 + (lane >> 4) * 4;
  int ocol0 = nt * 128 + wc * 64 + lrow;
#pragma unroll
  for (int m = 0; m < 4; ++m)
#pragma unroll
    for (int n = 0; n < 4; ++n)
#pragma unroll
      for (int r = 0; r < 4; ++r)
        out[(size_t)(orow0 + m * 16 + r) * 1024 + ocol0 + n * 16] = acc[m][n][r];
}

// ---------------------------------------------------------------- launch
extern "C" void kernel_launch(void* const* d_in, const int* in_sizes, int n_in,
                              void* d_out, int out_size, void* d_ws, size_t ws_size,
                              hipStream_t stream) {
  const float* x   = (const float*)d_in[0];
  const float* pe  = (const float*)d_in[1];
  const float* wso = (const float*)d_in[2];
  const float* wsv = (const float*)d_in[3];
  const float* Wq  = (const float*)d_in[4];
  const float* Wk  = (const float*)d_in[5];
  const float* Wv  = (const float*)d_in[6];
  const float* Wo  = (const float*)d_in[7];
  const float* Wp  = (const float*)d_in[8];
  float* out = (float*)d_out;
  char* ws = (char*)d_ws;

  // workspace carve-up (bytes), total 54,528,000 (< proven 56.6 MB)
  int*   cnt   = (int*)  (ws + 0);
  float* coefs = (float*)(ws + 4096);                       // 2 MiB
  int*   lidx  = (int*)  (ws + 2101248);                    // 8 MiB
  float* lg    = (float*)(ws + 10489856);                   // 8 MiB
  unsigned short* xb    = (unsigned short*)(ws + 18878464); // 8 MiB
  unsigned short* kposb = (unsigned short*)(ws + 27267072); // 2 MiB
  unsigned short* q     = (unsigned short*)(ws + 29362176); // 8 MiB (b,h,t,p)
  unsigned short* k     = (unsigned short*)(ws + 37750784); // 8 MiB
  unsigned short* v     = (unsigned short*)(ws + 46139392); // 8 MiB
  // aliases:
  unsigned short* peb = (unsigned short*)(ws + 29362176);   // 2 MiB over q (pre-proj)
  unsigned short* wpb = (unsigned short*)(ws + 31459328);   // 2 MiB over q (pre-proj)
  __hip_bfloat16* ctx = (__hip_bfloat16*)(ws + 2101248);    // 8 MiB over lidx
  __hip_bfloat16* Wob = (__hip_bfloat16*)(ws + 10489856);   // 16 MiB over lg+xb

  hipLaunchKernelGGL(zero_cnt_kernel, dim3(1), dim3(512), 0, stream, cnt);
  hipLaunchKernelGGL(gates_kernel, dim3(BT_ / 8), dim3(256), 0, stream,
                     x, wso, wsv, cnt, lidx, lg, coefs, xb);

  // kpos via bf16 MFMA (uses q region as scratch, before projections)
  hipLaunchKernelGGL(cvt_pos_kernel, dim3(R_ + 1024), dim3(256), 0, stream,
                     pe, Wp, peb, wpb);
  hipLaunchKernelGGL(kpos_mfma, dim3(5, 8), dim3(256), 0, stream, peb, wpb, kposb);

  hipLaunchKernelGGL(proj_mfma, dim3(128, 64), dim3(256), 0, stream,
                     xb, Wq, cnt, lidx, lg, q, 0, 0);
  hipLaunchKernelGGL(proj_mfma, dim3(128, 64), dim3(256), 0, stream,
                     xb, Wq, cnt, lidx, lg, q, 0, 1);
  hipLaunchKernelGGL(proj_mfma, dim3(128, 64), dim3(256), 0, stream,
                     xb, Wk, cnt, lidx, lg, k, 1, 0);
  hipLaunchKernelGGL(proj_mfma, dim3(128, 64), dim3(256), 0, stream,
                     xb, Wk, cnt, lidx, lg, k, 1, 1);
  hipLaunchKernelGGL(proj_mfma, dim3(128, 64), dim3(256), 0, stream,
                     xb, Wv, cnt, lidx, lg, v, 1, 0);
  hipLaunchKernelGGL(proj_mfma, dim3(128, 64), dim3(256), 0, stream,
                     xb, Wv, cnt, lidx, lg, v, 1, 1);

  hipLaunchKernelGGL(wo_transpose_kernel, dim3(128, 16), dim3(256), 0, stream,
                     Wo, (__hip_bfloat16*)Wob);

  hipLaunchKernelGGL(attn_mfma, dim3(8, 16, 8), dim3(256), 0, stream,
                     q, k, v, kposb, (unsigned short*)ctx);

  hipLaunchKernelGGL(moe_out_gemm, dim3(32, 8), dim3(256), 0, stream,
                     ctx, coefs, Wob, out);
}

// Round 6
// 816.264 us; speedup vs baseline: 7.2574x; 1.0793x over previous
//
#include <hip/hip_runtime.h>
#include <hip/hip_bf16.h>
#include <math.h>

#define H_ 16
#define E_ 8
#define D_ 1024
#define P_ 64
#define PV_ 64
#define B_ 8
#define T_ 512
#define R_ 1023
#define BT_ 4096
#define CAP_ 4096
#define PTILES_ 24

typedef __attribute__((ext_vector_type(8))) unsigned short ushort8;
typedef __attribute__((ext_vector_type(4))) unsigned short ushort4v;
typedef __attribute__((ext_vector_type(8))) short short8;
typedef __attribute__((ext_vector_type(4))) float f32x4;

__device__ inline float bf2f(unsigned short u) {
  union { unsigned int i; float f; } c; c.i = ((unsigned int)u) << 16; return c.f;
}
__device__ inline unsigned short f2bf(float f) {
  __hip_bfloat16 h = __float2bfloat16(f);
  return *reinterpret_cast<unsigned short*>(&h);
}

// ---------------------------------------------------------------- zero counts
__global__ void zero_cnt_kernel(int* __restrict__ cnt) {
  int i = threadIdx.x;
  if (i < 512) cnt[i] = 0;
}

// ---------------------------------------------------------------- gates (+x->bf16)
__global__ __launch_bounds__(256) void gates_kernel(
    const float* __restrict__ x, const float* __restrict__ wso,
    const float* __restrict__ wsv, int* __restrict__ cnt,
    int* __restrict__ lidx, float* __restrict__ lg,
    float* __restrict__ coefs, unsigned short* __restrict__ xbu) {
  __shared__ __align__(16) float xs[8][D_];
  __shared__ float gv[8][2][H_][E_];
  int tid = threadIdx.x;
  int bt0 = blockIdx.x * 8;

  const float4* xr = (const float4*)(x + (size_t)bt0 * D_);
  float4* xs4 = (float4*)xs;
  for (int i = tid; i < 2048; i += 256) {
    float4 w = xr[i];
    xs4[i] = w;
    ushort4v o = {f2bf(w.x), f2bf(w.y), f2bf(w.z), f2bf(w.w)};
    *(ushort4v*)&xbu[(size_t)bt0 * D_ + i * 4] = o;
  }
  __syncthreads();

  int set = tid >> 7, he = tid & 127;
  const float4* w4 = (const float4*)((set ? wsv : wso) + (size_t)he * D_);
  float acc[8] = {};
#pragma unroll 2
  for (int i = 0; i < 256; ++i) {
    float4 wv = w4[i];
#pragma unroll
    for (int r = 0; r < 8; ++r) {
      float4 xv = ((const float4*)xs[r])[i];
      acc[r] += xv.x * wv.x + xv.y * wv.y + xv.z * wv.z + xv.w * wv.w;
    }
  }
  int h = he >> 3, e = he & 7;
#pragma unroll
  for (int r = 0; r < 8; ++r)
    gv[r][set][h][e] = 1.f / (1.f + expf(-acc[r]));
  __syncthreads();

  {
    int r = tid >> 5, st = (tid >> 4) & 1, hh = tid & 15;
    int bt = bt0 + r;
    const float* g = gv[r][st][hh];
    int i1 = 0; float v1 = g[0];
    for (int ee = 1; ee < 8; ee++) if (g[ee] > v1) { v1 = g[ee]; i1 = ee; }
    int i2 = (i1 == 0) ? 1 : 0; float v2 = g[i2];
    for (int ee = 0; ee < 8; ee++) {
      if (ee == i1) continue;
      if (g[ee] > v2) { v2 = g[ee]; i2 = ee; }
    }
    int base1 = ((st * H_ + hh) * E_ + i1) * 2 + 0;
    int p1 = atomicAdd(&cnt[base1], 1);
    lidx[(size_t)base1 * CAP_ + p1] = bt;
    lg[(size_t)base1 * CAP_ + p1] = v1;
    int base2 = ((st * H_ + hh) * E_ + i2) * 2 + 1;
    int p2 = atomicAdd(&cnt[base2], 1);
    lidx[(size_t)base2 * CAP_ + p2] = bt;
    lg[(size_t)base2 * CAP_ + p2] = v2;
    if (st == 0) {
#pragma unroll
      for (int ee = 0; ee < 8; ee++) {
        float c = (ee == i1) ? v1 : ((ee == i2) ? v2 : 0.f);
        coefs[((size_t)bt * H_ + hh) * E_ + ee] = c;
      }
    }
  }
}

// ---------------------------------------------------------------- proj q (MFMA)
__global__ __launch_bounds__(256) void proj_mfma(
    const unsigned short* __restrict__ xb, const float* __restrict__ W,
    const int* __restrict__ cnt, const int* __restrict__ lidx,
    const float* __restrict__ lg, unsigned short* __restrict__ out,
    int set, int slot) {
  int he = blockIdx.x, tile = blockIdx.y;
  int base = (set * 128 + he) * 2 + slot;
  int n = cnt[base];
  int start = tile * 64;
  if (start >= n) return;
  int m = min(64, n - start);

  __shared__ int ridx[64];
  __shared__ float rgs[64];
  __shared__ __align__(16) unsigned short As[64][72];
  __shared__ __align__(16) unsigned short Bs[64][72];
  int tid = threadIdx.x;
  if (tid < 64) {
    int vi = 0; float g = 0.f;
    if (tid < m) {
      vi = lidx[(size_t)base * CAP_ + start + tid];
      g = lg[(size_t)base * CAP_ + start + tid];
    }
    ridx[tid] = vi; rgs[tid] = g;
  }
  __syncthreads();

  int wave = tid >> 6, lane = tid & 63;
  int lr = lane & 15, lk = (lane >> 4) << 3;
  f32x4 acc[4] = {};
  const float* Wb = W + (size_t)he * D_ * P_;

  int sr = tid >> 2, sseg = (tid & 3) << 4;
  int c4 = (tid & 15) * 4;
  int drb = tid >> 4;

  for (int d0 = 0; d0 < D_; d0 += 64) {
    {
      const unsigned short* xrow = xb + (size_t)ridx[sr] * D_ + d0 + sseg;
      *(ushort8*)&As[sr][sseg] = *(const ushort8*)xrow;
      *(ushort8*)&As[sr][sseg + 8] = *(const ushort8*)(xrow + 8);
    }
#pragma unroll
    for (int pass = 0; pass < 4; ++pass) {
      int dr = pass * 16 + drb;
      float4 wv = *(const float4*)&Wb[(size_t)(d0 + dr) * P_ + c4];
      Bs[c4 + 0][dr] = f2bf(wv.x);
      Bs[c4 + 1][dr] = f2bf(wv.y);
      Bs[c4 + 2][dr] = f2bf(wv.z);
      Bs[c4 + 3][dr] = f2bf(wv.w);
    }
    __syncthreads();
#pragma unroll
    for (int kk = 0; kk < 2; ++kk) {
      short8 af = *(const short8*)&As[wave * 16 + lr][kk * 32 + lk];
#pragma unroll
      for (int nn = 0; nn < 4; ++nn) {
        short8 bf8 = *(const short8*)&Bs[nn * 16 + lr][kk * 32 + lk];
        acc[nn] = __builtin_amdgcn_mfma_f32_16x16x32_bf16(af, bf8, acc[nn], 0, 0, 0);
      }
    }
    __syncthreads();
  }

  int h = he >> 3;
#pragma unroll
  for (int r = 0; r < 4; ++r) {
    int row = wave * 16 + (lane >> 4) * 4 + r;
    if (row < m) {
      int bt = ridx[row]; float g = rgs[row];
      int b = bt >> 9, t = bt & 511;
      unsigned short* orow = out + ((size_t)((b * H_ + h) * T_) + t) * P_;
      if (slot == 0) {
#pragma unroll
        for (int nn = 0; nn < 4; ++nn)
          orow[nn * 16 + lr] = f2bf(g * acc[nn][r]);
      } else {
#pragma unroll
        for (int nn = 0; nn < 4; ++nn) {
          int c = nn * 16 + lr;
          orow[c] = f2bf(bf2f(orow[c]) + g * acc[nn][r]);
        }
      }
    }
  }
}

// ---------------------------------------------------------------- proj k+v fused
// set-1 lists are shared by k and v: stage A once, run both B/MFMA chains.
__global__ __launch_bounds__(256) void proj_kv_mfma(
    const unsigned short* __restrict__ xb, const float* __restrict__ Wk,
    const float* __restrict__ Wv, const int* __restrict__ cnt,
    const int* __restrict__ lidx, const float* __restrict__ lg,
    unsigned short* __restrict__ outk, unsigned short* __restrict__ outv,
    int slot) {
  int he = blockIdx.x, tile = blockIdx.y;
  int base = (128 + he) * 2 + slot;  // set = 1
  int n = cnt[base];
  int start = tile * 64;
  if (start >= n) return;
  int m = min(64, n - start);

  __shared__ int ridx[64];
  __shared__ float rgs[64];
  __shared__ __align__(16) unsigned short As[64][72];
  __shared__ __align__(16) unsigned short Bk[64][72];
  __shared__ __align__(16) unsigned short Bv[64][72];
  int tid = threadIdx.x;
  if (tid < 64) {
    int vi = 0; float g = 0.f;
    if (tid < m) {
      vi = lidx[(size_t)base * CAP_ + start + tid];
      g = lg[(size_t)base * CAP_ + start + tid];
    }
    ridx[tid] = vi; rgs[tid] = g;
  }
  __syncthreads();

  int wave = tid >> 6, lane = tid & 63;
  int lr = lane & 15, lk = (lane >> 4) << 3;
  f32x4 acck[4] = {}, accv[4] = {};
  const float* Wkb = Wk + (size_t)he * D_ * P_;
  const float* Wvb = Wv + (size_t)he * D_ * P_;

  int sr = tid >> 2, sseg = (tid & 3) << 4;
  int c4 = (tid & 15) * 4;
  int drb = tid >> 4;

  for (int d0 = 0; d0 < D_; d0 += 64) {
    {
      const unsigned short* xrow = xb + (size_t)ridx[sr] * D_ + d0 + sseg;
      *(ushort8*)&As[sr][sseg] = *(const ushort8*)xrow;
      *(ushort8*)&As[sr][sseg + 8] = *(const ushort8*)(xrow + 8);
    }
#pragma unroll
    for (int pass = 0; pass < 4; ++pass) {
      int dr = pass * 16 + drb;
      float4 wv = *(const float4*)&Wkb[(size_t)(d0 + dr) * P_ + c4];
      Bk[c4 + 0][dr] = f2bf(wv.x);
      Bk[c4 + 1][dr] = f2bf(wv.y);
      Bk[c4 + 2][dr] = f2bf(wv.z);
      Bk[c4 + 3][dr] = f2bf(wv.w);
      float4 wv2 = *(const float4*)&Wvb[(size_t)(d0 + dr) * P_ + c4];
      Bv[c4 + 0][dr] = f2bf(wv2.x);
      Bv[c4 + 1][dr] = f2bf(wv2.y);
      Bv[c4 + 2][dr] = f2bf(wv2.z);
      Bv[c4 + 3][dr] = f2bf(wv2.w);
    }
    __syncthreads();
#pragma unroll
    for (int kk = 0; kk < 2; ++kk) {
      short8 af = *(const short8*)&As[wave * 16 + lr][kk * 32 + lk];
#pragma unroll
      for (int nn = 0; nn < 4; ++nn) {
        short8 b1 = *(const short8*)&Bk[nn * 16 + lr][kk * 32 + lk];
        acck[nn] = __builtin_amdgcn_mfma_f32_16x16x32_bf16(af, b1, acck[nn], 0, 0, 0);
        short8 b2 = *(const short8*)&Bv[nn * 16 + lr][kk * 32 + lk];
        accv[nn] = __builtin_amdgcn_mfma_f32_16x16x32_bf16(af, b2, accv[nn], 0, 0, 0);
      }
    }
    __syncthreads();
  }

  int h = he >> 3;
#pragma unroll
  for (int r = 0; r < 4; ++r) {
    int row = wave * 16 + (lane >> 4) * 4 + r;
    if (row < m) {
      int bt = ridx[row]; float g = rgs[row];
      int b = bt >> 9, t = bt & 511;
      size_t off = ((size_t)((b * H_ + h) * T_) + t) * P_;
      unsigned short* okr = outk + off;
      unsigned short* ovr = outv + off;
      if (slot == 0) {
#pragma unroll
        for (int nn = 0; nn < 4; ++nn) {
          okr[nn * 16 + lr] = f2bf(g * acck[nn][r]);
          ovr[nn * 16 + lr] = f2bf(g * accv[nn][r]);
        }
      } else {
#pragma unroll
        for (int nn = 0; nn < 4; ++nn) {
          int c = nn * 16 + lr;
          okr[c] = f2bf(bf2f(okr[c]) + g * acck[nn][r]);
          ovr[c] = f2bf(bf2f(ovr[c]) + g * accv[nn][r]);
        }
      }
    }
  }
}

// ---------------------------------------------------------------- pe/Wpos -> bf16
__global__ __launch_bounds__(256) void cvt_pos_kernel(
    const float* __restrict__ pe, const float* __restrict__ Wp,
    unsigned short* __restrict__ peb, unsigned short* __restrict__ wpb) {
  int bid = blockIdx.x;
  const float* src;
  unsigned short* dst;
  if (bid < R_) { src = pe + (size_t)bid * D_; dst = peb + (size_t)bid * D_; }
  else { src = Wp + (size_t)(bid - R_) * D_; dst = wpb + (size_t)(bid - R_) * D_; }
  int tid = threadIdx.x;
  float4 w = ((const float4*)src)[tid];
  ushort4v o = {f2bf(w.x), f2bf(w.y), f2bf(w.z), f2bf(w.w)};
  *(ushort4v*)&dst[tid * 4] = o;
}

// ---------------------------------------------------------------- k_pos MFMA
__global__ __launch_bounds__(256) void kpos_mfma(
    const unsigned short* __restrict__ peb, const unsigned short* __restrict__ wpb,
    unsigned short* __restrict__ kposb) {
  __shared__ __align__(16) unsigned short As[128][72];
  __shared__ __align__(16) unsigned short Bs[128][72];
  int tid = threadIdx.x, mt = blockIdx.x, nt = blockIdx.y;
  int wave = tid >> 6, lane = tid & 63;
  int wr = wave >> 1, wc = wave & 1;
  int lrow = lane & 15, lk = (lane >> 4) << 3;
  f32x4 acc[4][4] = {};
  int arow = tid >> 1, aseg = (tid & 1) * 32;

  for (int d0 = 0; d0 < D_; d0 += 64) {
    const ushort8* asrc = (const ushort8*)&peb[((size_t)mt * 128 + arow) * D_ + d0 + aseg];
    const ushort8* bsrc = (const ushort8*)&wpb[((size_t)nt * 128 + arow) * D_ + d0 + aseg];
#pragma unroll
    for (int i = 0; i < 4; ++i) {
      *(ushort8*)&As[arow][aseg + i * 8] = asrc[i];
      *(ushort8*)&Bs[arow][aseg + i * 8] = bsrc[i];
    }
    __syncthreads();
#pragma unroll
    for (int kk = 0; kk < 2; ++kk) {
      short8 af[4], bfr[4];
#pragma unroll
      for (int m = 0; m < 4; ++m)
        af[m] = *(const short8*)&As[wr * 64 + m * 16 + lrow][kk * 32 + lk];
#pragma unroll
      for (int n = 0; n < 4; ++n)
        bfr[n] = *(const short8*)&Bs[wc * 64 + n * 16 + lrow][kk * 32 + lk];
#pragma unroll
      for (int m = 0; m < 4; ++m)
#pragma unroll
        for (int n = 0; n < 4; ++n)
          acc[m][n] = __builtin_amdgcn_mfma_f32_16x16x32_bf16(
              af[m], bfr[n], acc[m][n], 0, 0, 0);
    }
    __syncthreads();
  }

  int orow0 = mt * 128 + wr * 64 + (lane >> 4) * 4;
  int ocol0 = nt * 128 + wc * 64 + lrow;
#pragma unroll
  for (int m = 0; m < 4; ++m)
#pragma unroll
    for (int n = 0; n < 4; ++n)
#pragma unroll
      for (int r = 0; r < 4; ++r)
        kposb[(size_t)(orow0 + m * 16 + r) * 1024 + ocol0 + n * 16] =
            f2bf(acc[m][n][r]);
}

// ---------------------------------------------------------------- attention (MFMA flash)
__global__ __launch_bounds__(256) void attn_mfma(
    const unsigned short* __restrict__ q, const unsigned short* __restrict__ k,
    const unsigned short* __restrict__ v, const unsigned short* __restrict__ kposb,
    unsigned short* __restrict__ ctx) {
  int qt = blockIdx.x, h = blockIdx.y, b = blockIdx.z;
  int t0 = qt << 6;
  int tid = threadIdx.x, wave = tid >> 6, lane = tid & 63;
  int lr = lane & 15, lkg = lane >> 4;
  int lk = lkg << 3;

  __shared__ __align__(16) unsigned short Ks[64][72];
  __shared__ __align__(16) unsigned short VTs[64][72];
  __shared__ __align__(16) unsigned short Srl[64][136];

  size_t bh = (size_t)(b * H_ + h);
  const unsigned short* kb = k + bh * T_ * 64;
  const unsigned short* vb = v + bh * T_ * 64;
  const unsigned short* qb = q + bh * T_ * 64;

  short8 qf[2];
  {
    const unsigned short* qrow = qb + (size_t)(t0 + wave * 16 + lr) * 64;
    qf[0] = *(const short8*)&qrow[lk];
    qf[1] = *(const short8*)&qrow[32 + lk];
  }

  float m_run[4], l_run[4];
  f32x4 oacc[4];
#pragma unroll
  for (int r = 0; r < 4; ++r) { m_run[r] = -1e30f; l_run[r] = 0.f; }
#pragma unroll
  for (int nn = 0; nn < 4; ++nn) oacc[nn] = (f32x4){0.f, 0.f, 0.f, 0.f};

  int row_local = wave * 16 + lkg * 4;
  int sstg = tid >> 2, sseg = (tid & 3) << 4;

  for (int st = 0; st <= qt; ++st) {
    int s0 = st << 6;
    {
      const unsigned short* krow = kb + (size_t)(s0 + sstg) * 64 + sseg;
      *(ushort8*)&Ks[sstg][sseg] = *(const ushort8*)krow;
      *(ushort8*)&Ks[sstg][sseg + 8] = *(const ushort8*)(krow + 8);
      const unsigned short* vrow = vb + (size_t)(s0 + sstg) * 64 + sseg;
      ushort8 v0 = *(const ushort8*)vrow, v1 = *(const ushort8*)(vrow + 8);
#pragma unroll
      for (int j = 0; j < 8; ++j) VTs[sseg + j][sstg] = v0[j];
#pragma unroll
      for (int j = 0; j < 8; ++j) VTs[sseg + 8 + j][sstg] = v1[j];
    }
    __syncthreads();

    f32x4 sc[4] = {};
#pragma unroll
    for (int kk = 0; kk < 2; ++kk) {
#pragma unroll
      for (int nn = 0; nn < 4; ++nn) {
        short8 bfk = *(const short8*)&Ks[nn * 16 + lr][kk * 32 + lk];
        sc[nn] = __builtin_amdgcn_mfma_f32_16x16x32_bf16(qf[kk], bfk, sc[nn], 0, 0, 0);
      }
    }
    int r_base = s0 - t0 + 448;
    const unsigned short* kpb = kposb + (size_t)r_base * 1024 + h * 64;
    f32x4 srf[8] = {};
#pragma unroll
    for (int kk = 0; kk < 2; ++kk) {
#pragma unroll
      for (int nn = 0; nn < 8; ++nn) {
        short8 bfp = *(const short8*)&kpb[(size_t)(nn * 16 + lr) * 1024 + kk * 32 + lk];
        srf[nn] = __builtin_amdgcn_mfma_f32_16x16x32_bf16(qf[kk], bfp, srf[nn], 0, 0, 0);
      }
    }
#pragma unroll
    for (int nn = 0; nn < 8; ++nn)
#pragma unroll
      for (int r = 0; r < 4; ++r)
        Srl[row_local + r][nn * 16 + lr] = f2bf(srf[nn][r]);

    float sv[4][4];
#pragma unroll
    for (int nn = 0; nn < 4; ++nn) {
#pragma unroll
      for (int r = 0; r < 4; ++r) {
        int row = row_local + r;
        int scc = nn * 16 + lr;
        int rj = scc - row + 63;
        float spos = bf2f(Srl[row][rj]);
        float sval = (sc[nn][r] + spos) * 0.125f;
        sv[nn][r] = ((s0 + scc) <= (t0 + row)) ? sval : -1e9f;
      }
    }
    float alpha[4];
#pragma unroll
    for (int r = 0; r < 4; ++r) {
      float mx = fmaxf(fmaxf(sv[0][r], sv[1][r]), fmaxf(sv[2][r], sv[3][r]));
      mx = fmaxf(mx, __shfl_xor(mx, 1));
      mx = fmaxf(mx, __shfl_xor(mx, 2));
      mx = fmaxf(mx, __shfl_xor(mx, 4));
      mx = fmaxf(mx, __shfl_xor(mx, 8));
      float mn = fmaxf(m_run[r], mx);
      alpha[r] = __expf(m_run[r] - mn);
      m_run[r] = mn;
    }
    float psum[4] = {0.f, 0.f, 0.f, 0.f};
#pragma unroll
    for (int nn = 0; nn < 4; ++nn) {
#pragma unroll
      for (int r = 0; r < 4; ++r) {
        unsigned short pb = f2bf(__expf(sv[nn][r] - m_run[r]));
        Srl[row_local + r][64 + nn * 16 + lr] = pb;
        psum[r] += bf2f(pb);
      }
    }
#pragma unroll
    for (int r = 0; r < 4; ++r) {
      float s = psum[r];
      s += __shfl_xor(s, 1); s += __shfl_xor(s, 2);
      s += __shfl_xor(s, 4); s += __shfl_xor(s, 8);
      l_run[r] = l_run[r] * alpha[r] + s;
#pragma unroll
      for (int nn = 0; nn < 4; ++nn) oacc[nn][r] *= alpha[r];
    }
#pragma unroll
    for (int kk = 0; kk < 2; ++kk) {
      short8 pa = *(const short8*)&Srl[wave * 16 + lr][64 + kk * 32 + lk];
#pragma unroll
      for (int nn = 0; nn < 4; ++nn) {
        short8 bv = *(const short8*)&VTs[nn * 16 + lr][kk * 32 + lk];
        oacc[nn] = __builtin_amdgcn_mfma_f32_16x16x32_bf16(pa, bv, oacc[nn], 0, 0, 0);
      }
    }
    __syncthreads();
  }

#pragma unroll
  for (int r = 0; r < 4; ++r) {
    float inv = 1.f / l_run[r];
    int tg = t0 + row_local + r;
    unsigned short* crow = ctx + ((size_t)(b * T_ + tg) * H_ + h) * PV_;
#pragma unroll
    for (int nn = 0; nn < 4; ++nn)
      crow[nn * 16 + lr] = f2bf(oacc[nn][r] * inv);
  }
}

// ---------------------------------------------------------------- Wo transpose
__global__ __launch_bounds__(256) void wo_transpose_kernel(
    const float* __restrict__ Wo, __hip_bfloat16* __restrict__ Wob) {
  __shared__ float t[64][65];
  int kt = blockIdx.x, dt = blockIdx.y;
  int tid = threadIdx.x;
  int kr = tid >> 2, dseg = (tid & 3) * 16;
  const float4* src = (const float4*)&Wo[(size_t)(kt * 64 + kr) * 1024 + dt * 64 + dseg];
#pragma unroll
  for (int i = 0; i < 4; ++i) {
    float4 v4 = src[i];
    t[kr][dseg + i * 4 + 0] = v4.x;
    t[kr][dseg + i * 4 + 1] = v4.y;
    t[kr][dseg + i * 4 + 2] = v4.z;
    t[kr][dseg + i * 4 + 3] = v4.w;
  }
  __syncthreads();
  int dr = tid >> 2, kseg = (tid & 3) * 16;
  unsigned short* dst =
      (unsigned short*)Wob + (size_t)(dt * 64 + dr) * 8192 + kt * 64 + kseg;
#pragma unroll
  for (int half = 0; half < 2; ++half) {
    ushort8 o;
#pragma unroll
    for (int j = 0; j < 8; ++j) o[j] = f2bf(t[kseg + half * 8 + j][dr]);
    *(ushort8*)&dst[half * 8] = o;
  }
}

// ---------------------------------------------------------------- MoE out GEMM v2
// 512 threads, 8 waves (2M x 4N), tile 128x128, grid (32, 8).
__global__ __launch_bounds__(512) void moe_out_gemm(
    const __hip_bfloat16* __restrict__ ctx, const float* __restrict__ coefs,
    const __hip_bfloat16* __restrict__ Wob, float* __restrict__ out) {
  __shared__ __align__(16) unsigned short As[128][72];
  __shared__ __align__(16) unsigned short Bs[128][72];
  int tid = threadIdx.x;
  int mt = blockIdx.x, nt = blockIdx.y;
  int wave = tid >> 6, lane = tid & 63;
  int wr = wave >> 2, wc = wave & 3;      // 2 x 4 wave grid
  int lrow = lane & 15, lk = (lane >> 4) << 3;

  f32x4 acc[4][2] = {};

  int arow = tid >> 2;            // 0..127
  int aseg = (tid & 3) * 16;      // 16-elem segment
  const unsigned short* ctxu = (const unsigned short*)ctx;
  const unsigned short* wobu = (const unsigned short*)Wob;
  size_t grow = (size_t)mt * 128 + arow;

  for (int he = 0; he < 128; ++he) {
    int h = he >> 3;
    float cf = coefs[grow * 128 + he];
    const ushort8* asrc = (const ushort8*)&ctxu[(grow * 16 + h) * 64 + aseg];
    const ushort8* bsrc =
        (const ushort8*)&wobu[((size_t)nt * 128 + arow) * 8192 + he * 64 + aseg];
#pragma unroll
    for (int i = 0; i < 2; ++i) {
      ushort8 u = asrc[i];
      ushort8 o;
#pragma unroll
      for (int j = 0; j < 8; ++j) o[j] = f2bf(bf2f(u[j]) * cf);
      *(ushort8*)&As[arow][aseg + i * 8] = o;
      *(ushort8*)&Bs[arow][aseg + i * 8] = bsrc[i];
    }
    __syncthreads();
#pragma unroll
    for (int kk = 0; kk < 2; ++kk) {
      short8 af[4], bfr[2];
#pragma unroll
      for (int m = 0; m < 4; ++m)
        af[m] = *(const short8*)&As[wr * 64 + m * 16 + lrow][kk * 32 + lk];
#pragma unroll
      for (int n = 0; n < 2; ++n)
        bfr[n] = *(const short8*)&Bs[wc * 32 + n * 16 + lrow][kk * 32 + lk];
#pragma unroll
      for (int m = 0; m < 4; ++m)
#pragma unroll
        for (int n = 0; n < 2; ++n)
          acc[m][n] = __builtin_amdgcn_mfma_f32_16x16x32_bf16(
              af[m], bfr[n], acc[m][n], 0, 0, 0);
    }
    __syncthreads();
  }

  int orow0 = mt * 128 + wr * 64 + (lane >> 4) * 4;
  int ocol0 = nt * 128 + wc * 32 + lrow;
#pragma unroll
  for (int m = 0; m < 4; ++m)
#pragma unroll
    for (int n = 0; n < 2; ++n)
#pragma unroll
      for (int r = 0; r < 4; ++r)
        out[(size_t)(orow0 + m * 16 + r) * 1024 + ocol0 + n * 16] = acc[m][n][r];
}

// ---------------------------------------------------------------- launch
extern "C" void kernel_launch(void* const* d_in, const int* in_sizes, int n_in,
                              void* d_out, int out_size, void* d_ws, size_t ws_size,
                              hipStream_t stream) {
  const float* x   = (const float*)d_in[0];
  const float* pe  = (const float*)d_in[1];
  const float* wso = (const float*)d_in[2];
  const float* wsv = (const float*)d_in[3];
  const float* Wq  = (const float*)d_in[4];
  const float* Wk  = (const float*)d_in[5];
  const float* Wv  = (const float*)d_in[6];
  const float* Wo  = (const float*)d_in[7];
  const float* Wp  = (const float*)d_in[8];
  float* out = (float*)d_out;
  char* ws = (char*)d_ws;

  int*   cnt   = (int*)  (ws + 0);
  float* coefs = (float*)(ws + 4096);                       // 2 MiB
  int*   lidx  = (int*)  (ws + 2101248);                    // 8 MiB
  float* lg    = (float*)(ws + 10489856);                   // 8 MiB
  unsigned short* xb    = (unsigned short*)(ws + 18878464); // 8 MiB
  unsigned short* kposb = (unsigned short*)(ws + 27267072); // 2 MiB
  unsigned short* q     = (unsigned short*)(ws + 29362176); // 8 MiB (b,h,t,p)
  unsigned short* k     = (unsigned short*)(ws + 37750784); // 8 MiB
  unsigned short* v     = (unsigned short*)(ws + 46139392); // 8 MiB
  // aliases:
  unsigned short* peb = (unsigned short*)(ws + 29362176);   // 2 MiB over q (pre-proj)
  unsigned short* wpb = (unsigned short*)(ws + 31459328);   // 2 MiB over q (pre-proj)
  __hip_bfloat16* ctx = (__hip_bfloat16*)(ws + 2101248);    // 8 MiB over lidx
  __hip_bfloat16* Wob = (__hip_bfloat16*)(ws + 10489856);   // 16 MiB over lg+xb

  hipLaunchKernelGGL(zero_cnt_kernel, dim3(1), dim3(512), 0, stream, cnt);
  hipLaunchKernelGGL(gates_kernel, dim3(BT_ / 8), dim3(256), 0, stream,
                     x, wso, wsv, cnt, lidx, lg, coefs, xb);

  hipLaunchKernelGGL(cvt_pos_kernel, dim3(R_ + 1024), dim3(256), 0, stream,
                     pe, Wp, peb, wpb);
  hipLaunchKernelGGL(kpos_mfma, dim3(5, 8), dim3(256), 0, stream, peb, wpb, kposb);

  hipLaunchKernelGGL(proj_mfma, dim3(128, PTILES_), dim3(256), 0, stream,
                     xb, Wq, cnt, lidx, lg, q, 0, 0);
  hipLaunchKernelGGL(proj_mfma, dim3(128, PTILES_), dim3(256), 0, stream,
                     xb, Wq, cnt, lidx, lg, q, 0, 1);
  hipLaunchKernelGGL(proj_kv_mfma, dim3(128, PTILES_), dim3(256), 0, stream,
                     xb, Wk, Wv, cnt, lidx, lg, k, v, 0);
  hipLaunchKernelGGL(proj_kv_mfma, dim3(128, PTILES_), dim3(256), 0, stream,
                     xb, Wk, Wv, cnt, lidx, lg, k, v, 1);

  hipLaunchKernelGGL(wo_transpose_kernel, dim3(128, 16), dim3(256), 0, stream,
                     Wo, (__hip_bfloat16*)Wob);

  hipLaunchKernelGGL(attn_mfma, dim3(8, 16, 8), dim3(256), 0, stream,
                     q, k, v, kposb, (unsigned short*)ctx);

  hipLaunchKernelGGL(moe_out_gemm, dim3(32, 8), dim3(512), 0, stream,
                     ctx, coefs, Wob, out);
}

// Round 7
// 814.566 us; speedup vs baseline: 7.2725x; 1.0021x over previous
//
#include <hip/hip_runtime.h>
#include <hip/hip_bf16.h>
#include <math.h>

#define H_ 16
#define E_ 8
#define D_ 1024
#define P_ 64
#define PV_ 64
#define B_ 8
#define T_ 512
#define R_ 1023
#define BT_ 4096
#define CAP_ 4096
#define PTILES_ 24

typedef __attribute__((ext_vector_type(8))) unsigned short ushort8;
typedef __attribute__((ext_vector_type(4))) unsigned short ushort4v;
typedef __attribute__((ext_vector_type(8))) short short8;
typedef __attribute__((ext_vector_type(4))) float f32x4;

__device__ inline float bf2f(unsigned short u) {
  union { unsigned int i; float f; } c; c.i = ((unsigned int)u) << 16; return c.f;
}
__device__ inline unsigned short f2bf(float f) {
  __hip_bfloat16 h = __float2bfloat16(f);
  return *reinterpret_cast<unsigned short*>(&h);
}

// ---------------------------------------------------------------- zero counts
__global__ void zero_cnt_kernel(int* __restrict__ cnt) {
  int i = threadIdx.x;
  if (i < 512) cnt[i] = 0;
}

// ---------------------------------------------------------------- gates v3 (+x->bf16)
// 256 threads, 8 bt rows. Thread t: column he=(t&127) for BOTH sets,
// K-half (t>>7). One xs read feeds 2 weight streams -> VALU-bound.
__global__ __launch_bounds__(256) void gates_kernel(
    const float* __restrict__ x, const float* __restrict__ wso,
    const float* __restrict__ wsv, int* __restrict__ cnt,
    int* __restrict__ lidx, float* __restrict__ lg,
    float* __restrict__ coefs, unsigned short* __restrict__ xbu) {
  __shared__ __align__(16) float xs[8][D_];   // 32 KB
  __shared__ float part[256][17];             // 17 KB (pad 17 -> <=2-way)
  __shared__ float gv[8][2][H_][E_];          // 8 KB
  int tid = threadIdx.x;
  int bt0 = blockIdx.x * 8;

  const float4* xr = (const float4*)(x + (size_t)bt0 * D_);
  float4* xs4 = (float4*)xs;
  for (int i = tid; i < 2048; i += 256) {
    float4 w = xr[i];
    xs4[i] = w;
    ushort4v o = {f2bf(w.x), f2bf(w.y), f2bf(w.z), f2bf(w.w)};
    *(ushort4v*)&xbu[(size_t)bt0 * D_ + i * 4] = o;
  }
  __syncthreads();

  {
    int he = tid & 127;
    int k0 = (tid >> 7) * 128;  // K half, in float4 units
    const float4* w0 = (const float4*)(wso + (size_t)he * D_) + k0;
    const float4* w1 = (const float4*)(wsv + (size_t)he * D_) + k0;
    float a0[8] = {}, a1[8] = {};
    for (int i = 0; i < 128; ++i) {
      float4 wv0 = w0[i], wv1 = w1[i];
#pragma unroll
      for (int r = 0; r < 8; ++r) {
        float4 xv = ((const float4*)xs[r])[k0 + i];
        a0[r] += xv.x * wv0.x + xv.y * wv0.y + xv.z * wv0.z + xv.w * wv0.w;
        a1[r] += xv.x * wv1.x + xv.y * wv1.y + xv.z * wv1.z + xv.w * wv1.w;
      }
    }
#pragma unroll
    for (int r = 0; r < 8; ++r) {
      part[tid][r] = a0[r];
      part[tid][8 + r] = a1[r];
    }
  }
  __syncthreads();

  // combine K-halves + sigmoid: thread = (set, col)
  {
    int col = tid & 127, set = tid >> 7;
    int h = col >> 3, e = col & 7;
#pragma unroll
    for (int r = 0; r < 8; ++r) {
      float v = part[col][set * 8 + r] + part[col + 128][set * 8 + r];
      gv[r][set][h][e] = 1.f / (1.f + expf(-v));
    }
  }
  __syncthreads();

  // 256 threads = 8 rows x 2 sets x 16 heads : top-2 per (row,set,h)
  {
    int r = tid >> 5, st = (tid >> 4) & 1, hh = tid & 15;
    int bt = bt0 + r;
    const float* g = gv[r][st][hh];
    int i1 = 0; float v1 = g[0];
    for (int ee = 1; ee < 8; ee++) if (g[ee] > v1) { v1 = g[ee]; i1 = ee; }
    int i2 = (i1 == 0) ? 1 : 0; float v2 = g[i2];
    for (int ee = 0; ee < 8; ee++) {
      if (ee == i1) continue;
      if (g[ee] > v2) { v2 = g[ee]; i2 = ee; }
    }
    int base1 = ((st * H_ + hh) * E_ + i1) * 2 + 0;
    int p1 = atomicAdd(&cnt[base1], 1);
    lidx[(size_t)base1 * CAP_ + p1] = bt;
    lg[(size_t)base1 * CAP_ + p1] = v1;
    int base2 = ((st * H_ + hh) * E_ + i2) * 2 + 1;
    int p2 = atomicAdd(&cnt[base2], 1);
    lidx[(size_t)base2 * CAP_ + p2] = bt;
    lg[(size_t)base2 * CAP_ + p2] = v2;
    if (st == 0) {
#pragma unroll
      for (int ee = 0; ee < 8; ee++) {
        float c = (ee == i1) ? v1 : ((ee == i2) ? v2 : 0.f);
        coefs[((size_t)bt * H_ + hh) * E_ + ee] = c;
      }
    }
  }
}

// ---------------------------------------------------------------- proj q (MFMA)
__global__ __launch_bounds__(256) void proj_mfma(
    const unsigned short* __restrict__ xb, const float* __restrict__ W,
    const int* __restrict__ cnt, const int* __restrict__ lidx,
    const float* __restrict__ lg, unsigned short* __restrict__ out,
    int set, int slot) {
  int he = blockIdx.x, tile = blockIdx.y;
  int base = (set * 128 + he) * 2 + slot;
  int n = cnt[base];
  int start = tile * 64;
  if (start >= n) return;
  int m = min(64, n - start);

  __shared__ int ridx[64];
  __shared__ float rgs[64];
  __shared__ __align__(16) unsigned short As[64][72];
  __shared__ __align__(16) unsigned short Bs[64][72];
  int tid = threadIdx.x;
  if (tid < 64) {
    int vi = 0; float g = 0.f;
    if (tid < m) {
      vi = lidx[(size_t)base * CAP_ + start + tid];
      g = lg[(size_t)base * CAP_ + start + tid];
    }
    ridx[tid] = vi; rgs[tid] = g;
  }
  __syncthreads();

  int wave = tid >> 6, lane = tid & 63;
  int lr = lane & 15, lk = (lane >> 4) << 3;
  f32x4 acc[4] = {};
  const float* Wb = W + (size_t)he * D_ * P_;

  int sr = tid >> 2, sseg = (tid & 3) << 4;
  int c4 = (tid & 15) * 4;
  int drb = tid >> 4;

  for (int d0 = 0; d0 < D_; d0 += 64) {
    {
      const unsigned short* xrow = xb + (size_t)ridx[sr] * D_ + d0 + sseg;
      *(ushort8*)&As[sr][sseg] = *(const ushort8*)xrow;
      *(ushort8*)&As[sr][sseg + 8] = *(const ushort8*)(xrow + 8);
    }
#pragma unroll
    for (int pass = 0; pass < 4; ++pass) {
      int dr = pass * 16 + drb;
      float4 wv = *(const float4*)&Wb[(size_t)(d0 + dr) * P_ + c4];
      Bs[c4 + 0][dr] = f2bf(wv.x);
      Bs[c4 + 1][dr] = f2bf(wv.y);
      Bs[c4 + 2][dr] = f2bf(wv.z);
      Bs[c4 + 3][dr] = f2bf(wv.w);
    }
    __syncthreads();
#pragma unroll
    for (int kk = 0; kk < 2; ++kk) {
      short8 af = *(const short8*)&As[wave * 16 + lr][kk * 32 + lk];
#pragma unroll
      for (int nn = 0; nn < 4; ++nn) {
        short8 bf8 = *(const short8*)&Bs[nn * 16 + lr][kk * 32 + lk];
        acc[nn] = __builtin_amdgcn_mfma_f32_16x16x32_bf16(af, bf8, acc[nn], 0, 0, 0);
      }
    }
    __syncthreads();
  }

  int h = he >> 3;
#pragma unroll
  for (int r = 0; r < 4; ++r) {
    int row = wave * 16 + (lane >> 4) * 4 + r;
    if (row < m) {
      int bt = ridx[row]; float g = rgs[row];
      int b = bt >> 9, t = bt & 511;
      unsigned short* orow = out + ((size_t)((b * H_ + h) * T_) + t) * P_;
      if (slot == 0) {
#pragma unroll
        for (int nn = 0; nn < 4; ++nn)
          orow[nn * 16 + lr] = f2bf(g * acc[nn][r]);
      } else {
#pragma unroll
        for (int nn = 0; nn < 4; ++nn) {
          int c = nn * 16 + lr;
          orow[c] = f2bf(bf2f(orow[c]) + g * acc[nn][r]);
        }
      }
    }
  }
}

// ---------------------------------------------------------------- proj k+v fused
__global__ __launch_bounds__(256) void proj_kv_mfma(
    const unsigned short* __restrict__ xb, const float* __restrict__ Wk,
    const float* __restrict__ Wv, const int* __restrict__ cnt,
    const int* __restrict__ lidx, const float* __restrict__ lg,
    unsigned short* __restrict__ outk, unsigned short* __restrict__ outv,
    int slot) {
  int he = blockIdx.x, tile = blockIdx.y;
  int base = (128 + he) * 2 + slot;  // set = 1
  int n = cnt[base];
  int start = tile * 64;
  if (start >= n) return;
  int m = min(64, n - start);

  __shared__ int ridx[64];
  __shared__ float rgs[64];
  __shared__ __align__(16) unsigned short As[64][72];
  __shared__ __align__(16) unsigned short Bk[64][72];
  __shared__ __align__(16) unsigned short Bv[64][72];
  int tid = threadIdx.x;
  if (tid < 64) {
    int vi = 0; float g = 0.f;
    if (tid < m) {
      vi = lidx[(size_t)base * CAP_ + start + tid];
      g = lg[(size_t)base * CAP_ + start + tid];
    }
    ridx[tid] = vi; rgs[tid] = g;
  }
  __syncthreads();

  int wave = tid >> 6, lane = tid & 63;
  int lr = lane & 15, lk = (lane >> 4) << 3;
  f32x4 acck[4] = {}, accv[4] = {};
  const float* Wkb = Wk + (size_t)he * D_ * P_;
  const float* Wvb = Wv + (size_t)he * D_ * P_;

  int sr = tid >> 2, sseg = (tid & 3) << 4;
  int c4 = (tid & 15) * 4;
  int drb = tid >> 4;

  for (int d0 = 0; d0 < D_; d0 += 64) {
    {
      const unsigned short* xrow = xb + (size_t)ridx[sr] * D_ + d0 + sseg;
      *(ushort8*)&As[sr][sseg] = *(const ushort8*)xrow;
      *(ushort8*)&As[sr][sseg + 8] = *(const ushort8*)(xrow + 8);
    }
#pragma unroll
    for (int pass = 0; pass < 4; ++pass) {
      int dr = pass * 16 + drb;
      float4 wv = *(const float4*)&Wkb[(size_t)(d0 + dr) * P_ + c4];
      Bk[c4 + 0][dr] = f2bf(wv.x);
      Bk[c4 + 1][dr] = f2bf(wv.y);
      Bk[c4 + 2][dr] = f2bf(wv.z);
      Bk[c4 + 3][dr] = f2bf(wv.w);
      float4 wv2 = *(const float4*)&Wvb[(size_t)(d0 + dr) * P_ + c4];
      Bv[c4 + 0][dr] = f2bf(wv2.x);
      Bv[c4 + 1][dr] = f2bf(wv2.y);
      Bv[c4 + 2][dr] = f2bf(wv2.z);
      Bv[c4 + 3][dr] = f2bf(wv2.w);
    }
    __syncthreads();
#pragma unroll
    for (int kk = 0; kk < 2; ++kk) {
      short8 af = *(const short8*)&As[wave * 16 + lr][kk * 32 + lk];
#pragma unroll
      for (int nn = 0; nn < 4; ++nn) {
        short8 b1 = *(const short8*)&Bk[nn * 16 + lr][kk * 32 + lk];
        acck[nn] = __builtin_amdgcn_mfma_f32_16x16x32_bf16(af, b1, acck[nn], 0, 0, 0);
        short8 b2 = *(const short8*)&Bv[nn * 16 + lr][kk * 32 + lk];
        accv[nn] = __builtin_amdgcn_mfma_f32_16x16x32_bf16(af, b2, accv[nn], 0, 0, 0);
      }
    }
    __syncthreads();
  }

  int h = he >> 3;
#pragma unroll
  for (int r = 0; r < 4; ++r) {
    int row = wave * 16 + (lane >> 4) * 4 + r;
    if (row < m) {
      int bt = ridx[row]; float g = rgs[row];
      int b = bt >> 9, t = bt & 511;
      size_t off = ((size_t)((b * H_ + h) * T_) + t) * P_;
      unsigned short* okr = outk + off;
      unsigned short* ovr = outv + off;
      if (slot == 0) {
#pragma unroll
        for (int nn = 0; nn < 4; ++nn) {
          okr[nn * 16 + lr] = f2bf(g * acck[nn][r]);
          ovr[nn * 16 + lr] = f2bf(g * accv[nn][r]);
        }
      } else {
#pragma unroll
        for (int nn = 0; nn < 4; ++nn) {
          int c = nn * 16 + lr;
          okr[c] = f2bf(bf2f(okr[c]) + g * acck[nn][r]);
          ovr[c] = f2bf(bf2f(ovr[c]) + g * accv[nn][r]);
        }
      }
    }
  }
}

// ---------------------------------------------------------------- pe/Wpos -> bf16
__global__ __launch_bounds__(256) void cvt_pos_kernel(
    const float* __restrict__ pe, const float* __restrict__ Wp,
    unsigned short* __restrict__ peb, unsigned short* __restrict__ wpb) {
  int bid = blockIdx.x;
  const float* src;
  unsigned short* dst;
  if (bid < R_) { src = pe + (size_t)bid * D_; dst = peb + (size_t)bid * D_; }
  else { src = Wp + (size_t)(bid - R_) * D_; dst = wpb + (size_t)(bid - R_) * D_; }
  int tid = threadIdx.x;
  float4 w = ((const float4*)src)[tid];
  ushort4v o = {f2bf(w.x), f2bf(w.y), f2bf(w.z), f2bf(w.w)};
  *(ushort4v*)&dst[tid * 4] = o;
}

// ---------------------------------------------------------------- k_pos MFMA
__global__ __launch_bounds__(256) void kpos_mfma(
    const unsigned short* __restrict__ peb, const unsigned short* __restrict__ wpb,
    unsigned short* __restrict__ kposb) {
  __shared__ __align__(16) unsigned short As[128][72];
  __shared__ __align__(16) unsigned short Bs[128][72];
  int tid = threadIdx.x, mt = blockIdx.x, nt = blockIdx.y;
  int wave = tid >> 6, lane = tid & 63;
  int wr = wave >> 1, wc = wave & 1;
  int lrow = lane & 15, lk = (lane >> 4) << 3;
  f32x4 acc[4][4] = {};
  int arow = tid >> 1, aseg = (tid & 1) * 32;

  for (int d0 = 0; d0 < D_; d0 += 64) {
    const ushort8* asrc = (const ushort8*)&peb[((size_t)mt * 128 + arow) * D_ + d0 + aseg];
    const ushort8* bsrc = (const ushort8*)&wpb[((size_t)nt * 128 + arow) * D_ + d0 + aseg];
#pragma unroll
    for (int i = 0; i < 4; ++i) {
      *(ushort8*)&As[arow][aseg + i * 8] = asrc[i];
      *(ushort8*)&Bs[arow][aseg + i * 8] = bsrc[i];
    }
    __syncthreads();
#pragma unroll
    for (int kk = 0; kk < 2; ++kk) {
      short8 af[4], bfr[4];
#pragma unroll
      for (int m = 0; m < 4; ++m)
        af[m] = *(const short8*)&As[wr * 64 + m * 16 + lrow][kk * 32 + lk];
#pragma unroll
      for (int n = 0; n < 4; ++n)
        bfr[n] = *(const short8*)&Bs[wc * 64 + n * 16 + lrow][kk * 32 + lk];
#pragma unroll
      for (int m = 0; m < 4; ++m)
#pragma unroll
        for (int n = 0; n < 4; ++n)
          acc[m][n] = __builtin_amdgcn_mfma_f32_16x16x32_bf16(
              af[m], bfr[n], acc[m][n], 0, 0, 0);
    }
    __syncthreads();
  }

  int orow0 = mt * 128 + wr * 64 + (lane >> 4) * 4;
  int ocol0 = nt * 128 + wc * 64 + lrow;
#pragma unroll
  for (int m = 0; m < 4; ++m)
#pragma unroll
    for (int n = 0; n < 4; ++n)
#pragma unroll
      for (int r = 0; r < 4; ++r)
        kposb[(size_t)(orow0 + m * 16 + r) * 1024 + ocol0 + n * 16] =
            f2bf(acc[m][n][r]);
}

// ---------------------------------------------------------------- attention (MFMA flash)
__global__ __launch_bounds__(256) void attn_mfma(
    const unsigned short* __restrict__ q, const unsigned short* __restrict__ k,
    const unsigned short* __restrict__ v, const unsigned short* __restrict__ kposb,
    unsigned short* __restrict__ ctx) {
  int qt = blockIdx.x, h = blockIdx.y, b = blockIdx.z;
  int t0 = qt << 6;
  int tid = threadIdx.x, wave = tid >> 6, lane = tid & 63;
  int lr = lane & 15, lkg = lane >> 4;
  int lk = lkg << 3;

  __shared__ __align__(16) unsigned short Ks[64][72];
  __shared__ __align__(16) unsigned short VTs[64][72];
  __shared__ __align__(16) unsigned short Srl[64][136];

  size_t bh = (size_t)(b * H_ + h);
  const unsigned short* kb = k + bh * T_ * 64;
  const unsigned short* vb = v + bh * T_ * 64;
  const unsigned short* qb = q + bh * T_ * 64;

  short8 qf[2];
  {
    const unsigned short* qrow = qb + (size_t)(t0 + wave * 16 + lr) * 64;
    qf[0] = *(const short8*)&qrow[lk];
    qf[1] = *(const short8*)&qrow[32 + lk];
  }

  float m_run[4], l_run[4];
  f32x4 oacc[4];
#pragma unroll
  for (int r = 0; r < 4; ++r) { m_run[r] = -1e30f; l_run[r] = 0.f; }
#pragma unroll
  for (int nn = 0; nn < 4; ++nn) oacc[nn] = (f32x4){0.f, 0.f, 0.f, 0.f};

  int row_local = wave * 16 + lkg * 4;
  int sstg = tid >> 2, sseg = (tid & 3) << 4;

  for (int st = 0; st <= qt; ++st) {
    int s0 = st << 6;
    {
      const unsigned short* krow = kb + (size_t)(s0 + sstg) * 64 + sseg;
      *(ushort8*)&Ks[sstg][sseg] = *(const ushort8*)krow;
      *(ushort8*)&Ks[sstg][sseg + 8] = *(const ushort8*)(krow + 8);
      const unsigned short* vrow = vb + (size_t)(s0 + sstg) * 64 + sseg;
      ushort8 v0 = *(const ushort8*)vrow, v1 = *(const ushort8*)(vrow + 8);
#pragma unroll
      for (int j = 0; j < 8; ++j) VTs[sseg + j][sstg] = v0[j];
#pragma unroll
      for (int j = 0; j < 8; ++j) VTs[sseg + 8 + j][sstg] = v1[j];
    }
    __syncthreads();

    f32x4 sc[4] = {};
#pragma unroll
    for (int kk = 0; kk < 2; ++kk) {
#pragma unroll
      for (int nn = 0; nn < 4; ++nn) {
        short8 bfk = *(const short8*)&Ks[nn * 16 + lr][kk * 32 + lk];
        sc[nn] = __builtin_amdgcn_mfma_f32_16x16x32_bf16(qf[kk], bfk, sc[nn], 0, 0, 0);
      }
    }
    int r_base = s0 - t0 + 448;
    const unsigned short* kpb = kposb + (size_t)r_base * 1024 + h * 64;
    f32x4 srf[8] = {};
#pragma unroll
    for (int kk = 0; kk < 2; ++kk) {
#pragma unroll
      for (int nn = 0; nn < 8; ++nn) {
        short8 bfp = *(const short8*)&kpb[(size_t)(nn * 16 + lr) * 1024 + kk * 32 + lk];
        srf[nn] = __builtin_amdgcn_mfma_f32_16x16x32_bf16(qf[kk], bfp, srf[nn], 0, 0, 0);
      }
    }
#pragma unroll
    for (int nn = 0; nn < 8; ++nn)
#pragma unroll
      for (int r = 0; r < 4; ++r)
        Srl[row_local + r][nn * 16 + lr] = f2bf(srf[nn][r]);

    float sv[4][4];
#pragma unroll
    for (int nn = 0; nn < 4; ++nn) {
#pragma unroll
      for (int r = 0; r < 4; ++r) {
        int row = row_local + r;
        int scc = nn * 16 + lr;
        int rj = scc - row + 63;
        float spos = bf2f(Srl[row][rj]);
        float sval = (sc[nn][r] + spos) * 0.125f;
        sv[nn][r] = ((s0 + scc) <= (t0 + row)) ? sval : -1e9f;
      }
    }
    float alpha[4];
#pragma unroll
    for (int r = 0; r < 4; ++r) {
      float mx = fmaxf(fmaxf(sv[0][r], sv[1][r]), fmaxf(sv[2][r], sv[3][r]));
      mx = fmaxf(mx, __shfl_xor(mx, 1));
      mx = fmaxf(mx, __shfl_xor(mx, 2));
      mx = fmaxf(mx, __shfl_xor(mx, 4));
      mx = fmaxf(mx, __shfl_xor(mx, 8));
      float mn = fmaxf(m_run[r], mx);
      alpha[r] = __expf(m_run[r] - mn);
      m_run[r] = mn;
    }
    float psum[4] = {0.f, 0.f, 0.f, 0.f};
#pragma unroll
    for (int nn = 0; nn < 4; ++nn) {
#pragma unroll
      for (int r = 0; r < 4; ++r) {
        unsigned short pb = f2bf(__expf(sv[nn][r] - m_run[r]));
        Srl[row_local + r][64 + nn * 16 + lr] = pb;
        psum[r] += bf2f(pb);
      }
    }
#pragma unroll
    for (int r = 0; r < 4; ++r) {
      float s = psum[r];
      s += __shfl_xor(s, 1); s += __shfl_xor(s, 2);
      s += __shfl_xor(s, 4); s += __shfl_xor(s, 8);
      l_run[r] = l_run[r] * alpha[r] + s;
#pragma unroll
      for (int nn = 0; nn < 4; ++nn) oacc[nn][r] *= alpha[r];
    }
#pragma unroll
    for (int kk = 0; kk < 2; ++kk) {
      short8 pa = *(const short8*)&Srl[wave * 16 + lr][64 + kk * 32 + lk];
#pragma unroll
      for (int nn = 0; nn < 4; ++nn) {
        short8 bv = *(const short8*)&VTs[nn * 16 + lr][kk * 32 + lk];
        oacc[nn] = __builtin_amdgcn_mfma_f32_16x16x32_bf16(pa, bv, oacc[nn], 0, 0, 0);
      }
    }
    __syncthreads();
  }

#pragma unroll
  for (int r = 0; r < 4; ++r) {
    float inv = 1.f / l_run[r];
    int tg = t0 + row_local + r;
    unsigned short* crow = ctx + ((size_t)(b * T_ + tg) * H_ + h) * PV_;
#pragma unroll
    for (int nn = 0; nn < 4; ++nn)
      crow[nn * 16 + lr] = f2bf(oacc[nn][r] * inv);
  }
}

// ---------------------------------------------------------------- Wo transpose
__global__ __launch_bounds__(256) void wo_transpose_kernel(
    const float* __restrict__ Wo, __hip_bfloat16* __restrict__ Wob) {
  __shared__ float t[64][65];
  int kt = blockIdx.x, dt = blockIdx.y;
  int tid = threadIdx.x;
  int kr = tid >> 2, dseg = (tid & 3) * 16;
  const float4* src = (const float4*)&Wo[(size_t)(kt * 64 + kr) * 1024 + dt * 64 + dseg];
#pragma unroll
  for (int i = 0; i < 4; ++i) {
    float4 v4 = src[i];
    t[kr][dseg + i * 4 + 0] = v4.x;
    t[kr][dseg + i * 4 + 1] = v4.y;
    t[kr][dseg + i * 4 + 2] = v4.z;
    t[kr][dseg + i * 4 + 3] = v4.w;
  }
  __syncthreads();
  int dr = tid >> 2, kseg = (tid & 3) * 16;
  unsigned short* dst =
      (unsigned short*)Wob + (size_t)(dt * 64 + dr) * 8192 + kt * 64 + kseg;
#pragma unroll
  for (int half = 0; half < 2; ++half) {
    ushort8 o;
#pragma unroll
    for (int j = 0; j < 8; ++j) o[j] = f2bf(t[kseg + half * 8 + j][dr]);
    *(ushort8*)&dst[half * 8] = o;
  }
}

// ---------------------------------------------------------------- MoE out GEMM v2
__global__ __launch_bounds__(512) void moe_out_gemm(
    const __hip_bfloat16* __restrict__ ctx, const float* __restrict__ coefs,
    const __hip_bfloat16* __restrict__ Wob, float* __restrict__ out) {
  __shared__ __align__(16) unsigned short As[128][72];
  __shared__ __align__(16) unsigned short Bs[128][72];
  int tid = threadIdx.x;
  int mt = blockIdx.x, nt = blockIdx.y;
  int wave = tid >> 6, lane = tid & 63;
  int wr = wave >> 2, wc = wave & 3;
  int lrow = lane & 15, lk = (lane >> 4) << 3;

  f32x4 acc[4][2] = {};

  int arow = tid >> 2;
  int aseg = (tid & 3) * 16;
  const unsigned short* ctxu = (const unsigned short*)ctx;
  const unsigned short* wobu = (const unsigned short*)Wob;
  size_t grow = (size_t)mt * 128 + arow;

  for (int he = 0; he < 128; ++he) {
    int h = he >> 3;
    float cf = coefs[grow * 128 + he];
    const ushort8* asrc = (const ushort8*)&ctxu[(grow * 16 + h) * 64 + aseg];
    const ushort8* bsrc =
        (const ushort8*)&wobu[((size_t)nt * 128 + arow) * 8192 + he * 64 + aseg];
#pragma unroll
    for (int i = 0; i < 2; ++i) {
      ushort8 u = asrc[i];
      ushort8 o;
#pragma unroll
      for (int j = 0; j < 8; ++j) o[j] = f2bf(bf2f(u[j]) * cf);
      *(ushort8*)&As[arow][aseg + i * 8] = o;
      *(ushort8*)&Bs[arow][aseg + i * 8] = bsrc[i];
    }
    __syncthreads();
#pragma unroll
    for (int kk = 0; kk < 2; ++kk) {
      short8 af[4], bfr[2];
#pragma unroll
      for (int m = 0; m < 4; ++m)
        af[m] = *(const short8*)&As[wr * 64 + m * 16 + lrow][kk * 32 + lk];
#pragma unroll
      for (int n = 0; n < 2; ++n)
        bfr[n] = *(const short8*)&Bs[wc * 32 + n * 16 + lrow][kk * 32 + lk];
#pragma unroll
      for (int m = 0; m < 4; ++m)
#pragma unroll
        for (int n = 0; n < 2; ++n)
          acc[m][n] = __builtin_amdgcn_mfma_f32_16x16x32_bf16(
              af[m], bfr[n], acc[m][n], 0, 0, 0);
    }
    __syncthreads();
  }

  int orow0 = mt * 128 + wr * 64 + (lane >> 4) * 4;
  int ocol0 = nt * 128 + wc * 32 + lrow;
#pragma unroll
  for (int m = 0; m < 4; ++m)
#pragma unroll
    for (int n = 0; n < 2; ++n)
#pragma unroll
      for (int r = 0; r < 4; ++r)
        out[(size_t)(orow0 + m * 16 + r) * 1024 + ocol0 + n * 16] = acc[m][n][r];
}

// ---------------------------------------------------------------- launch
extern "C" void kernel_launch(void* const* d_in, const int* in_sizes, int n_in,
                              void* d_out, int out_size, void* d_ws, size_t ws_size,
                              hipStream_t stream) {
  const float* x   = (const float*)d_in[0];
  const float* pe  = (const float*)d_in[1];
  const float* wso = (const float*)d_in[2];
  const float* wsv = (const float*)d_in[3];
  const float* Wq  = (const float*)d_in[4];
  const float* Wk  = (const float*)d_in[5];
  const float* Wv  = (const float*)d_in[6];
  const float* Wo  = (const float*)d_in[7];
  const float* Wp  = (const float*)d_in[8];
  float* out = (float*)d_out;
  char* ws = (char*)d_ws;

  int*   cnt   = (int*)  (ws + 0);
  float* coefs = (float*)(ws + 4096);                       // 2 MiB
  int*   lidx  = (int*)  (ws + 2101248);                    // 8 MiB
  float* lg    = (float*)(ws + 10489856);                   // 8 MiB
  unsigned short* xb    = (unsigned short*)(ws + 18878464); // 8 MiB
  unsigned short* kposb = (unsigned short*)(ws + 27267072); // 2 MiB
  unsigned short* q     = (unsigned short*)(ws + 29362176); // 8 MiB (b,h,t,p)
  unsigned short* k     = (unsigned short*)(ws + 37750784); // 8 MiB
  unsigned short* v     = (unsigned short*)(ws + 46139392); // 8 MiB
  // aliases:
  unsigned short* peb = (unsigned short*)(ws + 29362176);   // 2 MiB over q (pre-proj)
  unsigned short* wpb = (unsigned short*)(ws + 31459328);   // 2 MiB over q (pre-proj)
  __hip_bfloat16* ctx = (__hip_bfloat16*)(ws + 2101248);    // 8 MiB over lidx
  __hip_bfloat16* Wob = (__hip_bfloat16*)(ws + 10489856);   // 16 MiB over lg+xb

  hipLaunchKernelGGL(zero_cnt_kernel, dim3(1), dim3(512), 0, stream, cnt);
  hipLaunchKernelGGL(gates_kernel, dim3(BT_ / 8), dim3(256), 0, stream,
                     x, wso, wsv, cnt, lidx, lg, coefs, xb);

  hipLaunchKernelGGL(cvt_pos_kernel, dim3(R_ + 1024), dim3(256), 0, stream,
                     pe, Wp, peb, wpb);
  hipLaunchKernelGGL(kpos_mfma, dim3(5, 8), dim3(256), 0, stream, peb, wpb, kposb);

  hipLaunchKernelGGL(proj_mfma, dim3(128, PTILES_), dim3(256), 0, stream,
                     xb, Wq, cnt, lidx, lg, q, 0, 0);
  hipLaunchKernelGGL(proj_mfma, dim3(128, PTILES_), dim3(256), 0, stream,
                     xb, Wq, cnt, lidx, lg, q, 0, 1);
  hipLaunchKernelGGL(proj_kv_mfma, dim3(128, PTILES_), dim3(256), 0, stream,
                     xb, Wk, Wv, cnt, lidx, lg, k, v, 0);
  hipLaunchKernelGGL(proj_kv_mfma, dim3(128, PTILES_), dim3(256), 0, stream,
                     xb, Wk, Wv, cnt, lidx, lg, k, v, 1);

  hipLaunchKernelGGL(wo_transpose_kernel, dim3(128, 16), dim3(256), 0, stream,
                     Wo, (__hip_bfloat16*)Wob);

  hipLaunchKernelGGL(attn_mfma, dim3(8, 16, 8), dim3(256), 0, stream,
                     q, k, v, kposb, (unsigned short*)ctx);

  hipLaunchKernelGGL(moe_out_gemm, dim3(32, 8), dim3(512), 0, stream,
                     ctx, coefs, Wob, out);
}